// Round 1
// baseline (7836.130 us; speedup 1.0000x reference)
//
// RNN_79577154060490 — round 2: persistent cooperative kernel
// h0 = p0@W_enc^T; 100x h=tanh(v@W_ih^T + h@W_hh^T); out = g@W_dec^T + b
//
// Change vs round 1: the 200 per-step launches (stepmm+steptanh) are replaced by
// ONE cooperative kernel (256 blocks x 512 thr, 1 block/CU). Each block keeps its
// 128 KB W_hh tile RESIDENT in LDS (loaded once) — kills the per-step 32 MB W
// restream (the 17 MB/dispatch FETCH_SIZE) and all W staging barriers. A-fragments
// are loaded global->VGPR directly (image layout = coalesced 16B frags, same-ks
// blocks share their A slice in their XCD's L2). Two grid.sync() per step replace
// the launch boundaries. Part stays fp32 (16 MB) through LLC.
//
// Fragment images (per 32KB chunk = 128 rows/cols x 128 k):
//   A-image: [chunk][mt(8)][ktl(4)][lane(64)][8]   lane = (k>>3 &3)*16 + (b&15)
//   B-image: [chunk][nt(8)][ktl(4)][lane(64)][8]   lane = (k>>3 &3)*16 + (c&15)
//
// ws layout (bytes):
//   [0,         33554432)   WhS  bf16 [gt32][chunk32][nt8][ktl4][64][8]
//   [33554432,  37748736)   WdS  bf16 [pt4][chunk32][nt8][ktl4][64][8]
//   [37748736,  38797312)   H0S  bf16 A-image (1MB)
//   [38797312, 143654912)   Gsw  bf16 [t100] A-images (100MB)
//   [143654912,160432128)   Part fp32 [ks8][128][4096] (16MB)

#include <hip/hip_runtime.h>
#include <hip/hip_cooperative_groups.h>
#include <stdint.h>

namespace cg = cooperative_groups;

namespace {
constexpr int kT = 100;
constexpr int kNG = 4096;
constexpr int kNP = 512;

__device__ __forceinline__ uint16_t f2bf(float f) {
  uint32_t u = __float_as_uint(f);
  u += 0x7FFFu + ((u >> 16) & 1u);
  return (uint16_t)(u >> 16);
}

__device__ __forceinline__ float fast_tanh(float x) {
  float xc = fminf(fmaxf(x, -15.f), 15.f);
  float e = __expf(2.f * xc);
  return (e - 1.f) / (e + 1.f);
}

__device__ __forceinline__ void gl2lds16(const void* g, void* l) {
  __builtin_amdgcn_global_load_lds((const __attribute__((address_space(1))) unsigned int*)g,
                                   (__attribute__((address_space(3))) unsigned int*)l, 16, 0, 0);
}

// fragment-image element offsets (within one tensor)
__device__ __forceinline__ size_t a_img_off(int b, int g) {  // g = k index
  return ((size_t)(((g >> 7) * 8 + (b >> 4)) * 4 + ((g >> 5) & 3)) * 64 +
          ((g >> 3) & 3) * 16 + (b & 15)) * 8 + (g & 7);
}
}  // namespace

typedef short bf16x8 __attribute__((ext_vector_type(8)));
typedef float f32x4 __attribute__((ext_vector_type(4)));

// ---- swizzle-convert W_hh fp32 [4096][4096] -> WhS B-image bf16 ----
__global__ __launch_bounds__(512) void cvt_whh_kernel(const float* __restrict__ W,
                                                      uint16_t* __restrict__ WhS) {
  const int idx = blockIdx.x * 512 + threadIdx.x;  // 2M threads
  const int g = idx >> 9;
  const int k0 = (idx & 511) << 3;
  const float4 x = *(const float4*)(W + (size_t)g * kNG + k0);
  const float4 y = *(const float4*)(W + (size_t)g * kNG + k0 + 4);
  uint4 u;
  u.x = (uint32_t)f2bf(x.x) | ((uint32_t)f2bf(x.y) << 16);
  u.y = (uint32_t)f2bf(x.z) | ((uint32_t)f2bf(x.w) << 16);
  u.z = (uint32_t)f2bf(y.x) | ((uint32_t)f2bf(y.y) << 16);
  u.w = (uint32_t)f2bf(y.z) | ((uint32_t)f2bf(y.w) << 16);
  const int gt = g >> 7, c = g & 127;
  const int nt = c >> 4, col = c & 15;
  const int chunk = k0 >> 7, ktl = (k0 >> 5) & 3, half = (k0 >> 3) & 3;
  const size_t off = ((size_t)(((gt * 32 + chunk) * 8 + nt) * 4 + ktl) * 64 + half * 16 + col) * 8;
  *(uint4*)(WhS + off) = u;
}

// ---- swizzle-convert W_dec fp32 [512][4096] -> WdS B-image bf16 ----
__global__ __launch_bounds__(512) void cvt_wdec_kernel(const float* __restrict__ W,
                                                       uint16_t* __restrict__ WdS) {
  const int idx = blockIdx.x * 512 + threadIdx.x;  // 256K threads
  const int p = idx >> 9;
  const int k0 = (idx & 511) << 3;
  const float4 x = *(const float4*)(W + (size_t)p * kNG + k0);
  const float4 y = *(const float4*)(W + (size_t)p * kNG + k0 + 4);
  uint4 u;
  u.x = (uint32_t)f2bf(x.x) | ((uint32_t)f2bf(x.y) << 16);
  u.y = (uint32_t)f2bf(x.z) | ((uint32_t)f2bf(x.w) << 16);
  u.z = (uint32_t)f2bf(y.x) | ((uint32_t)f2bf(y.y) << 16);
  u.w = (uint32_t)f2bf(y.z) | ((uint32_t)f2bf(y.w) << 16);
  const int pt = p >> 7, c = p & 127;
  const int nt = c >> 4, col = c & 15;
  const int chunk = k0 >> 7, ktl = (k0 >> 5) & 3, half = (k0 >> 3) & 3;
  const size_t off = ((size_t)(((pt * 32 + chunk) * 8 + nt) * 4 + ktl) * 64 + half * 16 + col) * 8;
  *(uint4*)(WdS + off) = u;
}

// ---- encoder: H0S = A-image of p0 @ Wenc^T (bf16) ----
__global__ __launch_bounds__(512, 2) void enc_kernel(const float* __restrict__ p0,
                                                     const float* __restrict__ Wenc,
                                                     uint16_t* __restrict__ H0S) {
  __shared__ alignas(16) uint16_t Wlds[16 * 64 * 8];
  const int tid = threadIdx.x;
  const int g0 = blockIdx.x * 16;
  for (int f = tid; f < 16 * 64; f += 512) {
    const int kt = f >> 6, fl = f & 63;
    const int g = g0 + (fl & 15);
    const int k = kt * 32 + ((fl >> 4) << 3);
    const float* s = Wenc + (size_t)g * kNP + k;
    uint16_t* d = Wlds + f * 8;
#pragma unroll
    for (int j = 0; j < 8; j++) d[j] = f2bf(s[j]);
  }
  __syncthreads();
  const int wave = tid >> 6;
  const int lane = tid & 63;
  const int mrow = wave * 16 + (lane & 15);
  const float* arow = p0 + (size_t)mrow * kNP + ((lane >> 4) << 3);
  f32x4 acc = {0.f, 0.f, 0.f, 0.f};
#pragma unroll
  for (int kt = 0; kt < 16; kt++) {
    const float* ap = arow + kt * 32;
    bf16x8 a;
#pragma unroll
    for (int j = 0; j < 8; j++) a[j] = (short)f2bf(ap[j]);
    bf16x8 b = *(const bf16x8*)(Wlds + (kt * 64 + lane) * 8);
    acc = __builtin_amdgcn_mfma_f32_16x16x32_bf16(a, b, acc, 0, 0, 0);
  }
  const int gcol = g0 + (lane & 15);
  const int rbase = wave * 16 + ((lane >> 4) << 2);
#pragma unroll
  for (int r = 0; r < 4; r++) {
    H0S[a_img_off(rbase + r, gcol)] = f2bf(acc[r]);
  }
}

// ---- persistent RNN loop: 256 blocks (gt=bid>>3, ks=bid&7 => ks==XCD) ----
// LDS: 128 KB resident W tile (4 chunks). A frags loaded global->VGPR.
// Per step: mm -> Part(fp32) -> grid.sync -> reduce+tanh -> Gsw[t] -> grid.sync
__global__ __launch_bounds__(512, 2) void rnn_loop_kernel(const uint16_t* __restrict__ WhS,
                                                          const uint16_t* __restrict__ H0S,
                                                          uint16_t* __restrict__ Gsw,
                                                          float* __restrict__ Part,
                                                          const float* __restrict__ v,
                                                          const float* __restrict__ Wih) {
  extern __shared__ uint16_t wlds[];  // 131072 B = 4 chunks x 16384 elems
  cg::grid_group grid = cg::this_grid();
  const int tid = threadIdx.x;
  const int wave = tid >> 6, lane = tid & 63;
  const int bid = blockIdx.x;
  const int gt = bid >> 3, ks = bid & 7;  // ks = bid%8 = XCD (A-slice L2 locality)
  const int mg = wave >> 1, ng = wave & 1;

  // ---- one-time: load W tile (chunks ks*4..ks*4+3 of row gt) into LDS, linear
  {
    const uint16_t* src = WhS + ((size_t)gt << 19) + ((size_t)(ks * 4) << 14);
#pragma unroll
    for (int i = 0; i < 16; i++) {
      const int j = wave * 16 + i;  // 128 rows x 1KB
      gl2lds16(src + (j << 9) + (lane << 3), (void*)(wlds + (j << 9)));
    }
  }
  __syncthreads();  // drains vmcnt before barrier (compiler-enforced)

  // reduce-phase coords: block handles b=bid>>1, g in [ (bid&1)*2048 , +2048 )
  const int rb2 = bid >> 1;
  const int rg0 = ((bid & 1) << 11) + (tid << 2);

  for (int t = 0; t < kT; t++) {
    const uint16_t* Aimg = (t == 0) ? H0S : (Gsw + (((size_t)(t - 1)) << 19));
    f32x4 acc[2][4];
#pragma unroll
    for (int i = 0; i < 2; i++)
#pragma unroll
      for (int j = 0; j < 4; j++) acc[i][j] = (f32x4){0.f, 0.f, 0.f, 0.f};

#pragma unroll
    for (int kc = 0; kc < 4; kc++) {
      const uint16_t* Ac = Aimg + ((size_t)(ks * 4 + kc) << 14);
      bf16x8 a[2][4];
#pragma unroll
      for (int mi = 0; mi < 2; mi++)
#pragma unroll
        for (int ktl = 0; ktl < 4; ktl++)
          a[mi][ktl] = *(const bf16x8*)(Ac + ((((mg * 2 + mi) * 4 + ktl) * 64 + lane) << 3));
#pragma unroll
      for (int ktl = 0; ktl < 4; ktl++) {
#pragma unroll
        for (int nt = 0; nt < 4; nt++) {
          bf16x8 b = *(const bf16x8*)(wlds + (kc << 14) +
                                      ((((ng * 4 + nt) * 4 + ktl) * 64 + lane) << 3));
          acc[0][nt] = __builtin_amdgcn_mfma_f32_16x16x32_bf16(a[0][ktl], b, acc[0][nt], 0, 0, 0);
          acc[1][nt] = __builtin_amdgcn_mfma_f32_16x16x32_bf16(a[1][ktl], b, acc[1][nt], 0, 0, 0);
        }
      }
    }
    // Part write (same layout as old stepmm)
    {
      const int g0 = (gt << 7) + (ng << 6);
      const int rb = (mg << 5) + ((lane >> 4) << 2);
#pragma unroll
      for (int mi = 0; mi < 2; mi++)
#pragma unroll
        for (int nt = 0; nt < 4; nt++)
#pragma unroll
          for (int r = 0; r < 4; r++) {
            const int b = rb + (mi << 4) + r;
            const int g = g0 + (nt << 4) + (lane & 15);
            Part[(((size_t)(ks * 128 + b)) << 12) + g] = acc[mi][nt][r];
          }
    }
    grid.sync();

    // ---- reduce + vin + tanh -> Gsw[t] A-image (4 g per thread)
    {
      float4 s = {0.f, 0.f, 0.f, 0.f};
#pragma unroll
      for (int k2 = 0; k2 < 8; k2++) {
        const float4 p = *(const float4*)(Part + ((size_t)((k2 << 7) + rb2) << 12) + rg0);
        s.x += p.x;
        s.y += p.y;
        s.z += p.z;
        s.w += p.w;
      }
      const float v0 = v[(rb2 * kT + t) * 2 + 0];
      const float v1 = v[(rb2 * kT + t) * 2 + 1];
      const float4 w0 = *(const float4*)(Wih + rg0 * 2);
      const float4 w1 = *(const float4*)(Wih + rg0 * 2 + 4);
      uint16_t h0 = f2bf(fast_tanh(s.x + v0 * w0.x + v1 * w0.y));
      uint16_t h1 = f2bf(fast_tanh(s.y + v0 * w0.z + v1 * w0.w));
      uint16_t h2 = f2bf(fast_tanh(s.z + v0 * w1.x + v1 * w1.y));
      uint16_t h3 = f2bf(fast_tanh(s.w + v0 * w1.z + v1 * w1.w));
      uint2 u;
      u.x = (uint32_t)h0 | ((uint32_t)h1 << 16);
      u.y = (uint32_t)h2 | ((uint32_t)h3 << 16);
      uint16_t* Gt = Gsw + (((size_t)t) << 19);
      *(uint2*)(Gt + a_img_off(rb2, rg0)) = u;
    }
    grid.sync();
  }
}

// ---- fallback step kernels (used only if cooperative launch is refused) ----
__global__ __launch_bounds__(512, 4) void stepmm_kernel(const uint16_t* __restrict__ Asrc,
                                                        const uint16_t* __restrict__ WhS,
                                                        float* __restrict__ Part) {
  __shared__ alignas(16) uint16_t lds[32768];  // 64KB: [0,16384)=A, [16384,32768)=B
  const int tid = threadIdx.x;
  const int wave = tid >> 6, lane = tid & 63;
  const int gt = blockIdx.x >> 3, ks = blockIdx.x & 7;
  const int mg = wave >> 1, ng = wave & 1;
  const uint16_t* Wbase = WhS + ((size_t)gt << 19);
  f32x4 acc[2][4];
#pragma unroll
  for (int i = 0; i < 2; i++)
#pragma unroll
    for (int j = 0; j < 4; j++) acc[i][j] = (f32x4){0.f, 0.f, 0.f, 0.f};

  for (int kc = 0; kc < 4; kc++) {
    const int chunk = ks * 4 + kc;
    const uint16_t* Ac = Asrc + ((size_t)chunk << 14);
    const uint16_t* Bc = Wbase + ((size_t)chunk << 14);
#pragma unroll
    for (int i = 0; i < 8; i++) {
      const int j = wave * 8 + i;  // wave-uniform
      const uint16_t* s = (j < 32) ? (Ac + (j << 9)) : (Bc + ((j - 32) << 9));
      gl2lds16(s + (lane << 3), (void*)(lds + (j << 9)));
    }
    __syncthreads();
    const uint16_t* lA = lds;
    const uint16_t* lB = lds + 16384;
#pragma unroll
    for (int ktl = 0; ktl < 4; ktl++) {
      bf16x8 a0 = *(const bf16x8*)(lA + ((((mg * 2 + 0) * 4 + ktl) * 64 + lane) << 3));
      bf16x8 a1 = *(const bf16x8*)(lA + ((((mg * 2 + 1) * 4 + ktl) * 64 + lane) << 3));
#pragma unroll
      for (int nt = 0; nt < 4; nt++) {
        bf16x8 b = *(const bf16x8*)(lB + ((((ng * 4 + nt) * 4 + ktl) * 64 + lane) << 3));
        acc[0][nt] = __builtin_amdgcn_mfma_f32_16x16x32_bf16(a0, b, acc[0][nt], 0, 0, 0);
        acc[1][nt] = __builtin_amdgcn_mfma_f32_16x16x32_bf16(a1, b, acc[1][nt], 0, 0, 0);
      }
    }
    __syncthreads();
  }
  const int g0 = (gt << 7) + (ng << 6);
  const int rb = (mg << 5) + ((lane >> 4) << 2);
#pragma unroll
  for (int mi = 0; mi < 2; mi++)
#pragma unroll
    for (int nt = 0; nt < 4; nt++)
#pragma unroll
      for (int r = 0; r < 4; r++) {
        const int b = rb + (mi << 4) + r;
        const int g = g0 + (nt << 4) + (lane & 15);
        Part[(((size_t)(ks * 128 + b)) << 12) + g] = acc[mi][nt][r];
      }
}

__global__ __launch_bounds__(256) void steptanh_kernel(const float* __restrict__ Part,
                                                       const float* __restrict__ v,
                                                       const float* __restrict__ Wih,
                                                       uint16_t* __restrict__ Gt, int t) {
  const int tg = blockIdx.x * 256 + threadIdx.x;  // 65536
  const int b = tg >> 9;
  const int g0 = (tg & 511) << 3;
  float s[8];
#pragma unroll
  for (int j = 0; j < 8; j++) s[j] = 0.f;
#pragma unroll
  for (int ks = 0; ks < 8; ks++) {
    const float4* p = (const float4*)(Part + (((size_t)(ks * 128 + b)) << 12) + g0);
    const float4 x = p[0], y = p[1];
    s[0] += x.x; s[1] += x.y; s[2] += x.z; s[3] += x.w;
    s[4] += y.x; s[5] += y.y; s[6] += y.z; s[7] += y.w;
  }
  const float v0 = v[(b * kT + t) * 2 + 0];
  const float v1 = v[(b * kT + t) * 2 + 1];
  uint16_t h[8];
#pragma unroll
  for (int j = 0; j < 8; j++) {
    const int g = g0 + j;
    const float pre = s[j] + v0 * Wih[g * 2 + 0] + v1 * Wih[g * 2 + 1];
    h[j] = f2bf(fast_tanh(pre));
  }
  uint4 u;
  u.x = (uint32_t)h[0] | ((uint32_t)h[1] << 16);
  u.y = (uint32_t)h[2] | ((uint32_t)h[3] << 16);
  u.z = (uint32_t)h[4] | ((uint32_t)h[5] << 16);
  u.w = (uint32_t)h[6] | ((uint32_t)h[7] << 16);
  const size_t off = ((size_t)(((g0 >> 7) * 8 + (b >> 4)) * 4 + ((g0 >> 5) & 3)) * 64 +
                      ((g0 >> 3) & 3) * 16 + (b & 15)) * 8;
  *(uint4*)(Gt + off) = u;
}

// ---- decoder: out[b,t,p] = Gsw[t] @ WdS[pt] + bias. block=(t, pt), 32 k-chunks ----
__global__ __launch_bounds__(512, 4) void dec_kernel(const uint16_t* __restrict__ Gsw,
                                                     const uint16_t* __restrict__ WdS,
                                                     const float* __restrict__ bd,
                                                     float* __restrict__ out) {
  __shared__ alignas(16) uint16_t lds[32768];
  const int tid = threadIdx.x;
  const int wave = tid >> 6, lane = tid & 63;
  const int t = blockIdx.x >> 2, pt = blockIdx.x & 3;
  const int mg = wave >> 1, ng = wave & 1;
  const uint16_t* Abase = Gsw + (size_t)t * 524288;
  const uint16_t* Bbase = WdS + (size_t)pt * 524288;
  f32x4 acc[2][4];
#pragma unroll
  for (int i = 0; i < 2; i++)
#pragma unroll
    for (int j = 0; j < 4; j++) acc[i][j] = (f32x4){0.f, 0.f, 0.f, 0.f};

  for (int chunk = 0; chunk < 32; chunk++) {
    const uint16_t* Ac = Abase + ((size_t)chunk << 14);
    const uint16_t* Bc = Bbase + ((size_t)chunk << 14);
#pragma unroll
    for (int i = 0; i < 8; i++) {
      const int j = wave * 8 + i;
      const uint16_t* s = (j < 32) ? (Ac + (j << 9)) : (Bc + ((j - 32) << 9));
      gl2lds16(s + (lane << 3), (void*)(lds + (j << 9)));
    }
    __syncthreads();
    const uint16_t* lA = lds;
    const uint16_t* lB = lds + 16384;
#pragma unroll
    for (int ktl = 0; ktl < 4; ktl++) {
      bf16x8 a0 = *(const bf16x8*)(lA + ((((mg * 2 + 0) * 4 + ktl) * 64 + lane) << 3));
      bf16x8 a1 = *(const bf16x8*)(lA + ((((mg * 2 + 1) * 4 + ktl) * 64 + lane) << 3));
#pragma unroll
      for (int nt = 0; nt < 4; nt++) {
        bf16x8 b = *(const bf16x8*)(lB + ((((ng * 4 + nt) * 4 + ktl) * 64 + lane) << 3));
        acc[0][nt] = __builtin_amdgcn_mfma_f32_16x16x32_bf16(a0, b, acc[0][nt], 0, 0, 0);
        acc[1][nt] = __builtin_amdgcn_mfma_f32_16x16x32_bf16(a1, b, acc[1][nt], 0, 0, 0);
      }
    }
    __syncthreads();
  }
  const int p0c = (pt << 7) + (ng << 6);
  const int rb = (mg << 5) + ((lane >> 4) << 2);
#pragma unroll
  for (int mi = 0; mi < 2; mi++)
#pragma unroll
    for (int nt = 0; nt < 4; nt++) {
      const int p = p0c + (nt << 4) + (lane & 15);
      const float bias = bd[p];
#pragma unroll
      for (int r = 0; r < 4; r++) {
        const int b = rb + (mi << 4) + r;
        out[((size_t)b * kT + t) * kNP + p] = acc[mi][nt][r] + bias;
      }
    }
}

extern "C" void kernel_launch(void* const* d_in, const int* in_sizes, int n_in,
                              void* d_out, int out_size, void* d_ws, size_t ws_size,
                              hipStream_t stream) {
  const float* v    = (const float*)d_in[0];
  const float* p0   = (const float*)d_in[1];
  const float* Wenc = (const float*)d_in[2];
  const float* Wih  = (const float*)d_in[3];
  const float* Whh  = (const float*)d_in[4];
  const float* Wdec = (const float*)d_in[5];
  const float* bdec = (const float*)d_in[6];
  float* out = (float*)d_out;

  uint8_t* ws = (uint8_t*)d_ws;
  uint16_t* WhS = (uint16_t*)(ws);
  uint16_t* WdS = (uint16_t*)(ws + 33554432);
  uint16_t* H0S = (uint16_t*)(ws + 37748736);
  uint16_t* Gsw = (uint16_t*)(ws + 38797312);
  float*    Part = (float*)(ws + 143654912);

  cvt_whh_kernel<<<4096, 512, 0, stream>>>(Whh, WhS);
  cvt_wdec_kernel<<<512, 512, 0, stream>>>(Wdec, WdS);
  enc_kernel<<<256, 512, 0, stream>>>(p0, Wenc, H0S);

  // persistent cooperative RNN loop (2 grid syncs per step)
  const uint16_t* WhS_c = WhS;
  const uint16_t* H0S_c = H0S;
  void* args[6] = {(void*)&WhS_c, (void*)&H0S_c, (void*)&Gsw, (void*)&Part,
                   (void*)&v, (void*)&Wih};
  hipError_t e = hipLaunchCooperativeKernel(rnn_loop_kernel, dim3(256), dim3(512), args,
                                            (unsigned int)131072, stream);
  if (e != hipSuccess) {
    // fallback: per-step launches (previous round's path)
    (void)hipGetLastError();
    for (int t = 0; t < kT; t++) {
      const uint16_t* Asrc = (t == 0) ? H0S : (Gsw + (size_t)(t - 1) * 524288);
      stepmm_kernel<<<256, 512, 0, stream>>>(Asrc, WhS, Part);
      steptanh_kernel<<<256, 256, 0, stream>>>(Part, v, Wih, Gsw + (size_t)t * 524288, t);
    }
  }

  dec_kernel<<<400, 512, 0, stream>>>(Gsw, WdS, bdec, out);
}

// Round 2
// 2577.778 us; speedup vs baseline: 3.0399x; 3.0399x over previous
//
// RNN_79577154060490 — round 3: persistent kernel, flag sync, XCD-local Part
// h0 = p0@W_enc^T; 100x h=tanh(v@W_ih^T + h@W_hh^T); out = g@W_dec^T + b
//
// Round-2 post-mortem: grid.sync's agent release/acquire flushed+invalidated L2
// every half-step -> the 16MB Part did a full HBM round trip per step (WRITE
// 18.4 MB/step) at 1 block/CU => 79 us/step, sync-flush-bound.
// Round-3 changes:
//  * block remap: gt=(bid&7)*4+(bid>>6), ks=(bid>>3)&7 — all 8 producers AND
//    reducers of a gt-tile on ONE XCD (bid%8 == XCD heuristic; perf-only).
//  * Part compact [gt][ks][128b][128g] fp32, produced+consumed in-XCD.
//  * no grid.sync: monotone flag counters. pcnt[gt]: Part ready (8/step);
//    hcnt[gt]: h-chunk ready (8/step) + doubles as WAR gate for Part reuse.
//    Producers signal with RELEASE (wbl2: only their ~64KB dirty), consumers
//    spin RELAXED then one agent-acquire (buffer_inv) ONLY on the Part path.
//    A-image reads need no acquire: addresses are fresh per t, data pushed to
//    LLC by the producers' release.
//  * W_hh stays LDS-resident (128 KB/block, loaded once).
//
// ws layout (bytes):
//   [0,         33554432)   WhS  bf16 [gt32][chunk32][nt8][ktl4][64][8]
//   [33554432,  37748736)   WdS  bf16 [pt4][chunk32][nt8][ktl4][64][8]
//   [37748736,  38797312)   H0S  bf16 A-image (1MB)
//   [38797312, 143654912)   Gsw  bf16 [t100] A-images (100MB)
//   [143654912,160432128)   Part fp32 [gt32][ks8][128][128] (16MB)
//   [160432128,160440320)   flags int[2048] (pcnt[32], hcnt[32]; stride 32)

#include <hip/hip_runtime.h>
#include <stdint.h>

namespace {
constexpr int kT = 100;
constexpr int kNG = 4096;
constexpr int kNP = 512;

__device__ __forceinline__ uint16_t f2bf(float f) {
  uint32_t u = __float_as_uint(f);
  u += 0x7FFFu + ((u >> 16) & 1u);
  return (uint16_t)(u >> 16);
}

__device__ __forceinline__ float fast_tanh(float x) {
  float xc = fminf(fmaxf(x, -15.f), 15.f);
  float e = __expf(2.f * xc);
  return (e - 1.f) / (e + 1.f);
}

__device__ __forceinline__ void gl2lds16(const void* g, void* l) {
  __builtin_amdgcn_global_load_lds((const __attribute__((address_space(1))) unsigned int*)g,
                                   (__attribute__((address_space(3))) unsigned int*)l, 16, 0, 0);
}

// fragment-image element offsets (within one tensor)
__device__ __forceinline__ size_t a_img_off(int b, int g) {  // g = k index
  return ((size_t)(((g >> 7) * 8 + (b >> 4)) * 4 + ((g >> 5) & 3)) * 64 +
          ((g >> 3) & 3) * 16 + (b & 15)) * 8 + (g & 7);
}
}  // namespace

typedef short bf16x8 __attribute__((ext_vector_type(8)));
typedef float f32x4 __attribute__((ext_vector_type(4)));

// ---- swizzle-convert W_hh fp32 [4096][4096] -> WhS B-image bf16 (+flag zero) ----
__global__ __launch_bounds__(512) void cvt_whh_kernel(const float* __restrict__ W,
                                                      uint16_t* __restrict__ WhS,
                                                      int* __restrict__ flags) {
  if (blockIdx.x == 4095) {
    for (int i = threadIdx.x; i < 2048; i += 512) flags[i] = 0;
  }
  const int idx = blockIdx.x * 512 + threadIdx.x;  // 2M threads
  const int g = idx >> 9;
  const int k0 = (idx & 511) << 3;
  const float4 x = *(const float4*)(W + (size_t)g * kNG + k0);
  const float4 y = *(const float4*)(W + (size_t)g * kNG + k0 + 4);
  uint4 u;
  u.x = (uint32_t)f2bf(x.x) | ((uint32_t)f2bf(x.y) << 16);
  u.y = (uint32_t)f2bf(x.z) | ((uint32_t)f2bf(x.w) << 16);
  u.z = (uint32_t)f2bf(y.x) | ((uint32_t)f2bf(y.y) << 16);
  u.w = (uint32_t)f2bf(y.z) | ((uint32_t)f2bf(y.w) << 16);
  const int gt = g >> 7, c = g & 127;
  const int nt = c >> 4, col = c & 15;
  const int chunk = k0 >> 7, ktl = (k0 >> 5) & 3, half = (k0 >> 3) & 3;
  const size_t off = ((size_t)(((gt * 32 + chunk) * 8 + nt) * 4 + ktl) * 64 + half * 16 + col) * 8;
  *(uint4*)(WhS + off) = u;
}

// ---- swizzle-convert W_dec fp32 [512][4096] -> WdS B-image bf16 ----
__global__ __launch_bounds__(512) void cvt_wdec_kernel(const float* __restrict__ W,
                                                       uint16_t* __restrict__ WdS) {
  const int idx = blockIdx.x * 512 + threadIdx.x;  // 256K threads
  const int p = idx >> 9;
  const int k0 = (idx & 511) << 3;
  const float4 x = *(const float4*)(W + (size_t)p * kNG + k0);
  const float4 y = *(const float4*)(W + (size_t)p * kNG + k0 + 4);
  uint4 u;
  u.x = (uint32_t)f2bf(x.x) | ((uint32_t)f2bf(x.y) << 16);
  u.y = (uint32_t)f2bf(x.z) | ((uint32_t)f2bf(x.w) << 16);
  u.z = (uint32_t)f2bf(y.x) | ((uint32_t)f2bf(y.y) << 16);
  u.w = (uint32_t)f2bf(y.z) | ((uint32_t)f2bf(y.w) << 16);
  const int pt = p >> 7, c = p & 127;
  const int nt = c >> 4, col = c & 15;
  const int chunk = k0 >> 7, ktl = (k0 >> 5) & 3, half = (k0 >> 3) & 3;
  const size_t off = ((size_t)(((pt * 32 + chunk) * 8 + nt) * 4 + ktl) * 64 + half * 16 + col) * 8;
  *(uint4*)(WdS + off) = u;
}

// ---- encoder: H0S = A-image of p0 @ Wenc^T (bf16) ----
__global__ __launch_bounds__(512, 2) void enc_kernel(const float* __restrict__ p0,
                                                     const float* __restrict__ Wenc,
                                                     uint16_t* __restrict__ H0S) {
  __shared__ alignas(16) uint16_t Wlds[16 * 64 * 8];
  const int tid = threadIdx.x;
  const int g0 = blockIdx.x * 16;
  for (int f = tid; f < 16 * 64; f += 512) {
    const int kt = f >> 6, fl = f & 63;
    const int g = g0 + (fl & 15);
    const int k = kt * 32 + ((fl >> 4) << 3);
    const float* s = Wenc + (size_t)g * kNP + k;
    uint16_t* d = Wlds + f * 8;
#pragma unroll
    for (int j = 0; j < 8; j++) d[j] = f2bf(s[j]);
  }
  __syncthreads();
  const int wave = tid >> 6;
  const int lane = tid & 63;
  const int mrow = wave * 16 + (lane & 15);
  const float* arow = p0 + (size_t)mrow * kNP + ((lane >> 4) << 3);
  f32x4 acc = {0.f, 0.f, 0.f, 0.f};
#pragma unroll
  for (int kt = 0; kt < 16; kt++) {
    const float* ap = arow + kt * 32;
    bf16x8 a;
#pragma unroll
    for (int j = 0; j < 8; j++) a[j] = (short)f2bf(ap[j]);
    bf16x8 b = *(const bf16x8*)(Wlds + (kt * 64 + lane) * 8);
    acc = __builtin_amdgcn_mfma_f32_16x16x32_bf16(a, b, acc, 0, 0, 0);
  }
  const int gcol = g0 + (lane & 15);
  const int rbase = wave * 16 + ((lane >> 4) << 2);
#pragma unroll
  for (int r = 0; r < 4; r++) {
    H0S[a_img_off(rbase + r, gcol)] = f2bf(acc[r]);
  }
}

// ---- persistent RNN loop, flag-synced ----
__global__ __launch_bounds__(512, 2) void rnn_loop_kernel(const uint16_t* __restrict__ WhS,
                                                          const uint16_t* __restrict__ H0S,
                                                          uint16_t* __restrict__ Gsw,
                                                          float* __restrict__ Part,
                                                          const float* __restrict__ v,
                                                          const float* __restrict__ Wih,
                                                          int* __restrict__ flags) {
  extern __shared__ uint16_t wlds[];  // 131072 B
  const int tid = threadIdx.x;
  const int wave = tid >> 6, lane = tid & 63;
  const int bid = blockIdx.x;
  const int xcd = bid & 7;                 // dispatch round-robin heuristic (perf-only)
  const int gt = xcd * 4 + (bid >> 6);     // all 8 ks-blocks of gt on one XCD
  const int ks = (bid >> 3) & 7;
  const int mg = wave >> 1, ng = wave & 1;

  int* pcnt = flags;            // [gt] stride 32
  int* hcnt = flags + 32 * 32;  // [gt] stride 32

  // one-time: W tile (row gt, chunks ks*4..+3) -> LDS, linear copy
  {
    const uint16_t* src = WhS + ((size_t)gt << 19) + ((size_t)(ks * 4) << 14);
#pragma unroll
    for (int i = 0; i < 16; i++) {
      const int j = wave * 16 + i;
      gl2lds16(src + (j << 9) + (lane << 3), (void*)(wlds + (j << 9)));
    }
  }
  __syncthreads();

  // reduce-phase coords: 16 rows x 128 g per block, 4 g per thread
  const int rbred = ks * 16 + (tid >> 5);  // batch row
  const int gl = (tid & 31) << 2;          // local g 0..124
  const int gg = gt * 128 + gl;            // global g
  float* myPart = Part + (((size_t)(gt * 8 + ks)) << 14);

  for (int t = 0; t < kT; t++) {
    // wait: h(t-1) chunks 4ks..4ks+3 ready; hcnt[gt] doubles as Part WAR gate
    if (t > 0) {
      const int target = 8 * t;
      if (tid < 5) {
        int* f = (tid < 4) ? (hcnt + ((ks * 4 + tid) << 5)) : (hcnt + (gt << 5));
        while (__hip_atomic_load(f, __ATOMIC_RELAXED, __HIP_MEMORY_SCOPE_AGENT) < target)
          __builtin_amdgcn_s_sleep(1);
      }
      __builtin_amdgcn_fence(__ATOMIC_ACQUIRE, "workgroup");  // compiler order; no cache op
      __syncthreads();
    }

    const uint16_t* Aimg = (t == 0) ? H0S : (Gsw + (((size_t)(t - 1)) << 19));
    f32x4 acc[2][4];
#pragma unroll
    for (int i = 0; i < 2; i++)
#pragma unroll
      for (int j = 0; j < 4; j++) acc[i][j] = (f32x4){0.f, 0.f, 0.f, 0.f};

#pragma unroll
    for (int kc = 0; kc < 4; kc++) {
      const uint16_t* Ac = Aimg + ((size_t)(ks * 4 + kc) << 14);
      bf16x8 a[2][4];
#pragma unroll
      for (int mi = 0; mi < 2; mi++)
#pragma unroll
        for (int ktl = 0; ktl < 4; ktl++)
          a[mi][ktl] = *(const bf16x8*)(Ac + ((((mg * 2 + mi) * 4 + ktl) * 64 + lane) << 3));
#pragma unroll
      for (int ktl = 0; ktl < 4; ktl++) {
#pragma unroll
        for (int nt = 0; nt < 4; nt++) {
          bf16x8 b = *(const bf16x8*)(wlds + (kc << 14) +
                                      ((((ng * 4 + nt) * 4 + ktl) * 64 + lane) << 3));
          acc[0][nt] = __builtin_amdgcn_mfma_f32_16x16x32_bf16(a[0][ktl], b, acc[0][nt], 0, 0, 0);
          acc[1][nt] = __builtin_amdgcn_mfma_f32_16x16x32_bf16(a[1][ktl], b, acc[1][nt], 0, 0, 0);
        }
      }
    }
    // Part write: compact [b][g] 128x128 f32 (64 KB, stays in this XCD's L2/LLC)
    {
      const int gcol0 = (ng << 6);
      const int rbase = (mg << 5) + ((lane >> 4) << 2);
#pragma unroll
      for (int mi = 0; mi < 2; mi++)
#pragma unroll
        for (int nt = 0; nt < 4; nt++)
#pragma unroll
          for (int r = 0; r < 4; r++) {
            const int b = rbase + (mi << 4) + r;
            const int g = gcol0 + (nt << 4) + (lane & 15);
            myPart[(b << 7) + g] = acc[mi][nt][r];
          }
    }
    __syncthreads();  // all Part stores complete (per-wave vmcnt drain at barrier)
    if (tid == 0) {
      // signal Part ready (release: wbl2 flushes our ~64KB dirty), then wait peers
      __hip_atomic_fetch_add(pcnt + (gt << 5), 1, __ATOMIC_RELEASE, __HIP_MEMORY_SCOPE_AGENT);
      const int tgt = 8 * (t + 1);
      while (__hip_atomic_load(pcnt + (gt << 5), __ATOMIC_RELAXED, __HIP_MEMORY_SCOPE_AGENT) < tgt)
        __builtin_amdgcn_s_sleep(1);
      __builtin_amdgcn_fence(__ATOMIC_ACQUIRE, "agent");  // buffer_inv: see peers' Part
    }
    __syncthreads();

    // reduce rows [16ks..+16) over 8 slices + vin + tanh -> Gsw[t] A-image
    {
      float s0 = 0.f, s1 = 0.f, s2 = 0.f, s3 = 0.f;
      const float* pb = Part + (((size_t)(gt * 8)) << 14) + (rbred << 7) + gl;
#pragma unroll
      for (int j = 0; j < 8; j++) {
        const float4 p = *(const float4*)(pb + ((size_t)j << 14));
        s0 += p.x; s1 += p.y; s2 += p.z; s3 += p.w;
      }
      const float v0 = v[(rbred * kT + t) * 2 + 0];
      const float v1 = v[(rbred * kT + t) * 2 + 1];
      const float4 w0 = *(const float4*)(Wih + gg * 2);
      const float4 w1 = *(const float4*)(Wih + gg * 2 + 4);
      const uint16_t h0 = f2bf(fast_tanh(s0 + v0 * w0.x + v1 * w0.y));
      const uint16_t h1 = f2bf(fast_tanh(s1 + v0 * w0.z + v1 * w0.w));
      const uint16_t h2 = f2bf(fast_tanh(s2 + v0 * w1.x + v1 * w1.y));
      const uint16_t h3 = f2bf(fast_tanh(s3 + v0 * w1.z + v1 * w1.w));
      uint2 u;
      u.x = (uint32_t)h0 | ((uint32_t)h1 << 16);
      u.y = (uint32_t)h2 | ((uint32_t)h3 << 16);
      uint16_t* Gt = Gsw + (((size_t)t) << 19);
      *(uint2*)(Gt + a_img_off(rbred, gg)) = u;
    }
    __syncthreads();  // h stores + Part reads complete
    if (tid == 0)
      __hip_atomic_fetch_add(hcnt + (gt << 5), 1, __ATOMIC_RELEASE, __HIP_MEMORY_SCOPE_AGENT);
  }
}

// ---- fallback step kernels (used only if cooperative launch is refused) ----
__global__ __launch_bounds__(512, 4) void stepmm_kernel(const uint16_t* __restrict__ Asrc,
                                                        const uint16_t* __restrict__ WhS,
                                                        float* __restrict__ Part) {
  __shared__ alignas(16) uint16_t lds[32768];
  const int tid = threadIdx.x;
  const int wave = tid >> 6, lane = tid & 63;
  const int gt = blockIdx.x >> 3, ks = blockIdx.x & 7;
  const int mg = wave >> 1, ng = wave & 1;
  const uint16_t* Wbase = WhS + ((size_t)gt << 19);
  f32x4 acc[2][4];
#pragma unroll
  for (int i = 0; i < 2; i++)
#pragma unroll
    for (int j = 0; j < 4; j++) acc[i][j] = (f32x4){0.f, 0.f, 0.f, 0.f};

  for (int kc = 0; kc < 4; kc++) {
    const int chunk = ks * 4 + kc;
    const uint16_t* Ac = Asrc + ((size_t)chunk << 14);
    const uint16_t* Bc = Wbase + ((size_t)chunk << 14);
#pragma unroll
    for (int i = 0; i < 8; i++) {
      const int j = wave * 8 + i;
      const uint16_t* s = (j < 32) ? (Ac + (j << 9)) : (Bc + ((j - 32) << 9));
      gl2lds16(s + (lane << 3), (void*)(lds + (j << 9)));
    }
    __syncthreads();
    const uint16_t* lA = lds;
    const uint16_t* lB = lds + 16384;
#pragma unroll
    for (int ktl = 0; ktl < 4; ktl++) {
      bf16x8 a0 = *(const bf16x8*)(lA + ((((mg * 2 + 0) * 4 + ktl) * 64 + lane) << 3));
      bf16x8 a1 = *(const bf16x8*)(lA + ((((mg * 2 + 1) * 4 + ktl) * 64 + lane) << 3));
#pragma unroll
      for (int nt = 0; nt < 4; nt++) {
        bf16x8 b = *(const bf16x8*)(lB + ((((ng * 4 + nt) * 4 + ktl) * 64 + lane) << 3));
        acc[0][nt] = __builtin_amdgcn_mfma_f32_16x16x32_bf16(a0, b, acc[0][nt], 0, 0, 0);
        acc[1][nt] = __builtin_amdgcn_mfma_f32_16x16x32_bf16(a1, b, acc[1][nt], 0, 0, 0);
      }
    }
    __syncthreads();
  }
  const int g0 = (gt << 7) + (ng << 6);
  const int rb = (mg << 5) + ((lane >> 4) << 2);
#pragma unroll
  for (int mi = 0; mi < 2; mi++)
#pragma unroll
    for (int nt = 0; nt < 4; nt++)
#pragma unroll
      for (int r = 0; r < 4; r++) {
        const int b = rb + (mi << 4) + r;
        const int g = g0 + (nt << 4) + (lane & 15);
        Part[(((size_t)(ks * 128 + b)) << 12) + g] = acc[mi][nt][r];
      }
}

__global__ __launch_bounds__(256) void steptanh_kernel(const float* __restrict__ Part,
                                                       const float* __restrict__ v,
                                                       const float* __restrict__ Wih,
                                                       uint16_t* __restrict__ Gt, int t) {
  const int tg = blockIdx.x * 256 + threadIdx.x;
  const int b = tg >> 9;
  const int g0 = (tg & 511) << 3;
  float s[8];
#pragma unroll
  for (int j = 0; j < 8; j++) s[j] = 0.f;
#pragma unroll
  for (int ks = 0; ks < 8; ks++) {
    const float4* p = (const float4*)(Part + (((size_t)(ks * 128 + b)) << 12) + g0);
    const float4 x = p[0], y = p[1];
    s[0] += x.x; s[1] += x.y; s[2] += x.z; s[3] += x.w;
    s[4] += y.x; s[5] += y.y; s[6] += y.z; s[7] += y.w;
  }
  const float v0 = v[(b * kT + t) * 2 + 0];
  const float v1 = v[(b * kT + t) * 2 + 1];
  uint16_t h[8];
#pragma unroll
  for (int j = 0; j < 8; j++) {
    const int g = g0 + j;
    const float pre = s[j] + v0 * Wih[g * 2 + 0] + v1 * Wih[g * 2 + 1];
    h[j] = f2bf(fast_tanh(pre));
  }
  uint4 u;
  u.x = (uint32_t)h[0] | ((uint32_t)h[1] << 16);
  u.y = (uint32_t)h[2] | ((uint32_t)h[3] << 16);
  u.z = (uint32_t)h[4] | ((uint32_t)h[5] << 16);
  u.w = (uint32_t)h[6] | ((uint32_t)h[7] << 16);
  const size_t off = ((size_t)(((g0 >> 7) * 8 + (b >> 4)) * 4 + ((g0 >> 5) & 3)) * 64 +
                      ((g0 >> 3) & 3) * 16 + (b & 15)) * 8;
  *(uint4*)(Gt + off) = u;
}

// ---- decoder: out[b,t,p] = Gsw[t] @ WdS[pt] + bias. block=(t, pt), 32 k-chunks ----
__global__ __launch_bounds__(512, 4) void dec_kernel(const uint16_t* __restrict__ Gsw,
                                                     const uint16_t* __restrict__ WdS,
                                                     const float* __restrict__ bd,
                                                     float* __restrict__ out) {
  __shared__ alignas(16) uint16_t lds[32768];
  const int tid = threadIdx.x;
  const int wave = tid >> 6, lane = tid & 63;
  const int t = blockIdx.x >> 2, pt = blockIdx.x & 3;
  const int mg = wave >> 1, ng = wave & 1;
  const uint16_t* Abase = Gsw + (size_t)t * 524288;
  const uint16_t* Bbase = WdS + (size_t)pt * 524288;
  f32x4 acc[2][4];
#pragma unroll
  for (int i = 0; i < 2; i++)
#pragma unroll
    for (int j = 0; j < 4; j++) acc[i][j] = (f32x4){0.f, 0.f, 0.f, 0.f};

  for (int chunk = 0; chunk < 32; chunk++) {
    const uint16_t* Ac = Abase + ((size_t)chunk << 14);
    const uint16_t* Bc = Bbase + ((size_t)chunk << 14);
#pragma unroll
    for (int i = 0; i < 8; i++) {
      const int j = wave * 8 + i;
      const uint16_t* s = (j < 32) ? (Ac + (j << 9)) : (Bc + ((j - 32) << 9));
      gl2lds16(s + (lane << 3), (void*)(lds + (j << 9)));
    }
    __syncthreads();
    const uint16_t* lA = lds;
    const uint16_t* lB = lds + 16384;
#pragma unroll
    for (int ktl = 0; ktl < 4; ktl++) {
      bf16x8 a0 = *(const bf16x8*)(lA + ((((mg * 2 + 0) * 4 + ktl) * 64 + lane) << 3));
      bf16x8 a1 = *(const bf16x8*)(lA + ((((mg * 2 + 1) * 4 + ktl) * 64 + lane) << 3));
#pragma unroll
      for (int nt = 0; nt < 4; nt++) {
        bf16x8 b = *(const bf16x8*)(lB + ((((ng * 4 + nt) * 4 + ktl) * 64 + lane) << 3));
        acc[0][nt] = __builtin_amdgcn_mfma_f32_16x16x32_bf16(a0, b, acc[0][nt], 0, 0, 0);
        acc[1][nt] = __builtin_amdgcn_mfma_f32_16x16x32_bf16(a1, b, acc[1][nt], 0, 0, 0);
      }
    }
    __syncthreads();
  }
  const int p0c = (pt << 7) + (ng << 6);
  const int rb = (mg << 5) + ((lane >> 4) << 2);
#pragma unroll
  for (int mi = 0; mi < 2; mi++)
#pragma unroll
    for (int nt = 0; nt < 4; nt++) {
      const int p = p0c + (nt << 4) + (lane & 15);
      const float bias = bd[p];
#pragma unroll
      for (int r = 0; r < 4; r++) {
        const int b = rb + (mi << 4) + r;
        out[((size_t)b * kT + t) * kNP + p] = acc[mi][nt][r] + bias;
      }
    }
}

extern "C" void kernel_launch(void* const* d_in, const int* in_sizes, int n_in,
                              void* d_out, int out_size, void* d_ws, size_t ws_size,
                              hipStream_t stream) {
  const float* v    = (const float*)d_in[0];
  const float* p0   = (const float*)d_in[1];
  const float* Wenc = (const float*)d_in[2];
  const float* Wih  = (const float*)d_in[3];
  const float* Whh  = (const float*)d_in[4];
  const float* Wdec = (const float*)d_in[5];
  const float* bdec = (const float*)d_in[6];
  float* out = (float*)d_out;

  uint8_t* ws = (uint8_t*)d_ws;
  uint16_t* WhS = (uint16_t*)(ws);
  uint16_t* WdS = (uint16_t*)(ws + 33554432);
  uint16_t* H0S = (uint16_t*)(ws + 37748736);
  uint16_t* Gsw = (uint16_t*)(ws + 38797312);
  float*    Part = (float*)(ws + 143654912);
  int*      flags = (int*)(ws + 160432128);

  cvt_whh_kernel<<<4096, 512, 0, stream>>>(Whh, WhS, flags);
  cvt_wdec_kernel<<<512, 512, 0, stream>>>(Wdec, WdS);
  enc_kernel<<<256, 512, 0, stream>>>(p0, Wenc, H0S);

  // persistent flag-synced RNN loop (cooperative launch for residency guarantee)
  const uint16_t* WhS_c = WhS;
  const uint16_t* H0S_c = H0S;
  void* args[7] = {(void*)&WhS_c, (void*)&H0S_c, (void*)&Gsw, (void*)&Part,
                   (void*)&v, (void*)&Wih, (void*)&flags};
  hipError_t e = hipLaunchCooperativeKernel(rnn_loop_kernel, dim3(256), dim3(512), args,
                                            (unsigned int)131072, stream);
  if (e != hipSuccess) {
    // fallback: per-step launches (round-1 path, ~1.96 ms class)
    (void)hipGetLastError();
    for (int t = 0; t < kT; t++) {
      const uint16_t* Asrc = (t == 0) ? H0S : (Gsw + (size_t)(t - 1) * 524288);
      stepmm_kernel<<<256, 512, 0, stream>>>(Asrc, WhS, Part);
      steptanh_kernel<<<256, 256, 0, stream>>>(Part, v, Wih, Gsw + (size_t)t * 524288, t);
    }
  }

  dec_kernel<<<400, 512, 0, stream>>>(Gsw, WdS, bdec, out);
}

// Round 3
// 2469.918 us; speedup vs baseline: 3.1726x; 1.0437x over previous
//
// RNN_79577154060490 — round 4: drop per-step buffer_inv; Part reads via sc0sc1 (LLC)
// h0 = p0@W_enc^T; 100x h=tanh(v@W_ih^T + h@W_hh^T); out = g@W_dec^T + b
//
// Round-3 post-mortem: 23.6 us/step, ~20 of it cache-maintenance latency:
// every block every step did 2x buffer_wbl2 (release adds) + 1x buffer_inv
// (acquire-agent fence). FETCH=4.4 MB/step proves the inv's refill traffic was
// LLC-absorbed -> the cost is op latency, not BW.
// Round-4 changes (minimal diff):
//  * DELETE the per-step fence(ACQUIRE,"agent") (buffer_inv). Replaced by:
//  * reduce-phase Part reads via inline-asm `global_load_dwordx4 ... sc0 sc1`
//    (coherent at LLC; bypasses stale L1/L2 copies of the address-reused Part).
//    Producer release-wbl2 already pushed Part to LLC, and the flag add is
//    issued post-wbl2, so flag-visible => data-in-LLC. Mapping-independent.
//  * A-image (Gsw) loads stay NORMAL cached: every Gsw[t] line is first-touched
//    after its producer's release within a replay, and dispatch-start L2
//    invalidate kills cross-replay staleness (round-1 per-step launches proved
//    dispatch boundaries give cross-XCD coherence).
//
// ws layout (bytes):
//   [0,         33554432)   WhS  bf16 [gt32][chunk32][nt8][ktl4][64][8]
//   [33554432,  37748736)   WdS  bf16 [pt4][chunk32][nt8][ktl4][64][8]
//   [37748736,  38797312)   H0S  bf16 A-image (1MB)
//   [38797312, 143654912)   Gsw  bf16 [t100] A-images (100MB)
//   [143654912,160432128)   Part fp32 [gt32][ks8][128][128] (16MB)
//   [160432128,160440320)   flags int[2048] (pcnt[32], hcnt[32]; stride 32)

#include <hip/hip_runtime.h>
#include <stdint.h>

namespace {
constexpr int kT = 100;
constexpr int kNG = 4096;
constexpr int kNP = 512;

__device__ __forceinline__ uint16_t f2bf(float f) {
  uint32_t u = __float_as_uint(f);
  u += 0x7FFFu + ((u >> 16) & 1u);
  return (uint16_t)(u >> 16);
}

__device__ __forceinline__ float fast_tanh(float x) {
  float xc = fminf(fmaxf(x, -15.f), 15.f);
  float e = __expf(2.f * xc);
  return (e - 1.f) / (e + 1.f);
}

__device__ __forceinline__ void gl2lds16(const void* g, void* l) {
  __builtin_amdgcn_global_load_lds((const __attribute__((address_space(1))) unsigned int*)g,
                                   (__attribute__((address_space(3))) unsigned int*)l, 16, 0, 0);
}

// fragment-image element offsets (within one tensor)
__device__ __forceinline__ size_t a_img_off(int b, int g) {  // g = k index
  return ((size_t)(((g >> 7) * 8 + (b >> 4)) * 4 + ((g >> 5) & 3)) * 64 +
          ((g >> 3) & 3) * 16 + (b & 15)) * 8 + (g & 7);
}
}  // namespace

typedef short bf16x8 __attribute__((ext_vector_type(8)));
typedef float f32x4 __attribute__((ext_vector_type(4)));

// ---- swizzle-convert W_hh fp32 [4096][4096] -> WhS B-image bf16 (+flag zero) ----
__global__ __launch_bounds__(512) void cvt_whh_kernel(const float* __restrict__ W,
                                                      uint16_t* __restrict__ WhS,
                                                      int* __restrict__ flags) {
  if (blockIdx.x == 4095) {
    for (int i = threadIdx.x; i < 2048; i += 512) flags[i] = 0;
  }
  const int idx = blockIdx.x * 512 + threadIdx.x;  // 2M threads
  const int g = idx >> 9;
  const int k0 = (idx & 511) << 3;
  const float4 x = *(const float4*)(W + (size_t)g * kNG + k0);
  const float4 y = *(const float4*)(W + (size_t)g * kNG + k0 + 4);
  uint4 u;
  u.x = (uint32_t)f2bf(x.x) | ((uint32_t)f2bf(x.y) << 16);
  u.y = (uint32_t)f2bf(x.z) | ((uint32_t)f2bf(x.w) << 16);
  u.z = (uint32_t)f2bf(y.x) | ((uint32_t)f2bf(y.y) << 16);
  u.w = (uint32_t)f2bf(y.z) | ((uint32_t)f2bf(y.w) << 16);
  const int gt = g >> 7, c = g & 127;
  const int nt = c >> 4, col = c & 15;
  const int chunk = k0 >> 7, ktl = (k0 >> 5) & 3, half = (k0 >> 3) & 3;
  const size_t off = ((size_t)(((gt * 32 + chunk) * 8 + nt) * 4 + ktl) * 64 + half * 16 + col) * 8;
  *(uint4*)(WhS + off) = u;
}

// ---- swizzle-convert W_dec fp32 [512][4096] -> WdS B-image bf16 ----
__global__ __launch_bounds__(512) void cvt_wdec_kernel(const float* __restrict__ W,
                                                       uint16_t* __restrict__ WdS) {
  const int idx = blockIdx.x * 512 + threadIdx.x;  // 256K threads
  const int p = idx >> 9;
  const int k0 = (idx & 511) << 3;
  const float4 x = *(const float4*)(W + (size_t)p * kNG + k0);
  const float4 y = *(const float4*)(W + (size_t)p * kNG + k0 + 4);
  uint4 u;
  u.x = (uint32_t)f2bf(x.x) | ((uint32_t)f2bf(x.y) << 16);
  u.y = (uint32_t)f2bf(x.z) | ((uint32_t)f2bf(x.w) << 16);
  u.z = (uint32_t)f2bf(y.x) | ((uint32_t)f2bf(y.y) << 16);
  u.w = (uint32_t)f2bf(y.z) | ((uint32_t)f2bf(y.w) << 16);
  const int pt = p >> 7, c = p & 127;
  const int nt = c >> 4, col = c & 15;
  const int chunk = k0 >> 7, ktl = (k0 >> 5) & 3, half = (k0 >> 3) & 3;
  const size_t off = ((size_t)(((pt * 32 + chunk) * 8 + nt) * 4 + ktl) * 64 + half * 16 + col) * 8;
  *(uint4*)(WdS + off) = u;
}

// ---- encoder: H0S = A-image of p0 @ Wenc^T (bf16) ----
__global__ __launch_bounds__(512, 2) void enc_kernel(const float* __restrict__ p0,
                                                     const float* __restrict__ Wenc,
                                                     uint16_t* __restrict__ H0S) {
  __shared__ alignas(16) uint16_t Wlds[16 * 64 * 8];
  const int tid = threadIdx.x;
  const int g0 = blockIdx.x * 16;
  for (int f = tid; f < 16 * 64; f += 512) {
    const int kt = f >> 6, fl = f & 63;
    const int g = g0 + (fl & 15);
    const int k = kt * 32 + ((fl >> 4) << 3);
    const float* s = Wenc + (size_t)g * kNP + k;
    uint16_t* d = Wlds + f * 8;
#pragma unroll
    for (int j = 0; j < 8; j++) d[j] = f2bf(s[j]);
  }
  __syncthreads();
  const int wave = tid >> 6;
  const int lane = tid & 63;
  const int mrow = wave * 16 + (lane & 15);
  const float* arow = p0 + (size_t)mrow * kNP + ((lane >> 4) << 3);
  f32x4 acc = {0.f, 0.f, 0.f, 0.f};
#pragma unroll
  for (int kt = 0; kt < 16; kt++) {
    const float* ap = arow + kt * 32;
    bf16x8 a;
#pragma unroll
    for (int j = 0; j < 8; j++) a[j] = (short)f2bf(ap[j]);
    bf16x8 b = *(const bf16x8*)(Wlds + (kt * 64 + lane) * 8);
    acc = __builtin_amdgcn_mfma_f32_16x16x32_bf16(a, b, acc, 0, 0, 0);
  }
  const int gcol = g0 + (lane & 15);
  const int rbase = wave * 16 + ((lane >> 4) << 2);
#pragma unroll
  for (int r = 0; r < 4; r++) {
    H0S[a_img_off(rbase + r, gcol)] = f2bf(acc[r]);
  }
}

// ---- persistent RNN loop, flag-synced; no per-step cache-maintenance ops ----
__global__ __launch_bounds__(512, 2) void rnn_loop_kernel(const uint16_t* __restrict__ WhS,
                                                          const uint16_t* __restrict__ H0S,
                                                          uint16_t* __restrict__ Gsw,
                                                          float* __restrict__ Part,
                                                          const float* __restrict__ v,
                                                          const float* __restrict__ Wih,
                                                          int* __restrict__ flags) {
  extern __shared__ uint16_t wlds[];  // 131072 B
  const int tid = threadIdx.x;
  const int wave = tid >> 6, lane = tid & 63;
  const int bid = blockIdx.x;
  const int xcd = bid & 7;                 // dispatch round-robin heuristic (perf-only)
  const int gt = xcd * 4 + (bid >> 6);     // all 8 ks-blocks of gt on one XCD
  const int ks = (bid >> 3) & 7;
  const int mg = wave >> 1, ng = wave & 1;

  int* pcnt = flags;            // [gt] stride 32
  int* hcnt = flags + 32 * 32;  // [gt] stride 32

  // one-time: W tile (row gt, chunks ks*4..+3) -> LDS, linear copy
  {
    const uint16_t* src = WhS + ((size_t)gt << 19) + ((size_t)(ks * 4) << 14);
#pragma unroll
    for (int i = 0; i < 16; i++) {
      const int j = wave * 16 + i;
      gl2lds16(src + (j << 9) + (lane << 3), (void*)(wlds + (j << 9)));
    }
  }
  __syncthreads();

  // reduce-phase coords: 16 rows x 128 g per block, 4 g per thread
  const int rbred = ks * 16 + (tid >> 5);  // batch row
  const int gl = (tid & 31) << 2;          // local g 0..124
  const int gg = gt * 128 + gl;            // global g
  float* myPart = Part + (((size_t)(gt * 8 + ks)) << 14);

  for (int t = 0; t < kT; t++) {
    // wait: h(t-1) chunks 4ks..4ks+3 ready; hcnt[gt] doubles as Part WAR gate
    if (t > 0) {
      const int target = 8 * t;
      if (tid < 5) {
        int* f = (tid < 4) ? (hcnt + ((ks * 4 + tid) << 5)) : (hcnt + (gt << 5));
        while (__hip_atomic_load(f, __ATOMIC_RELAXED, __HIP_MEMORY_SCOPE_AGENT) < target)
          __builtin_amdgcn_s_sleep(1);
      }
      __builtin_amdgcn_fence(__ATOMIC_ACQUIRE, "workgroup");  // compiler order; no cache op
      __syncthreads();
    }

    const uint16_t* Aimg = (t == 0) ? H0S : (Gsw + (((size_t)(t - 1)) << 19));
    f32x4 acc[2][4];
#pragma unroll
    for (int i = 0; i < 2; i++)
#pragma unroll
      for (int j = 0; j < 4; j++) acc[i][j] = (f32x4){0.f, 0.f, 0.f, 0.f};

#pragma unroll
    for (int kc = 0; kc < 4; kc++) {
      const uint16_t* Ac = Aimg + ((size_t)(ks * 4 + kc) << 14);
      bf16x8 a[2][4];
#pragma unroll
      for (int mi = 0; mi < 2; mi++)
#pragma unroll
        for (int ktl = 0; ktl < 4; ktl++)
          a[mi][ktl] = *(const bf16x8*)(Ac + ((((mg * 2 + mi) * 4 + ktl) * 64 + lane) << 3));
#pragma unroll
      for (int ktl = 0; ktl < 4; ktl++) {
#pragma unroll
        for (int nt = 0; nt < 4; nt++) {
          bf16x8 b = *(const bf16x8*)(wlds + (kc << 14) +
                                      ((((ng * 4 + nt) * 4 + ktl) * 64 + lane) << 3));
          acc[0][nt] = __builtin_amdgcn_mfma_f32_16x16x32_bf16(a[0][ktl], b, acc[0][nt], 0, 0, 0);
          acc[1][nt] = __builtin_amdgcn_mfma_f32_16x16x32_bf16(a[1][ktl], b, acc[1][nt], 0, 0, 0);
        }
      }
    }
    // Part write: compact [b][g] 128x128 f32 (normal cached stores; release-wbl2
    // below pushes them to LLC where the sc0sc1 reads will find them)
    {
      const int gcol0 = (ng << 6);
      const int rbase = (mg << 5) + ((lane >> 4) << 2);
#pragma unroll
      for (int mi = 0; mi < 2; mi++)
#pragma unroll
        for (int nt = 0; nt < 4; nt++)
#pragma unroll
          for (int r = 0; r < 4; r++) {
            const int b = rbase + (mi << 4) + r;
            const int g = gcol0 + (nt << 4) + (lane & 15);
            myPart[(b << 7) + g] = acc[mi][nt][r];
          }
    }
    __syncthreads();  // all Part stores complete (vmcnt drain at barrier)
    if (tid == 0) {
      // signal Part ready (release-agent: wbl2 pushes our dirty ~64KB to LLC)
      __hip_atomic_fetch_add(pcnt + (gt << 5), 1, __ATOMIC_RELEASE, __HIP_MEMORY_SCOPE_AGENT);
      const int tgt = 8 * (t + 1);
      while (__hip_atomic_load(pcnt + (gt << 5), __ATOMIC_RELAXED, __HIP_MEMORY_SCOPE_AGENT) < tgt)
        __builtin_amdgcn_s_sleep(1);
      // NOTE: no acquire-agent fence (no buffer_inv) — Part is read via sc0sc1
      // loads below, coherent at LLC by construction.
      __builtin_amdgcn_fence(__ATOMIC_ACQUIRE, "workgroup");  // compiler order only
    }
    __syncthreads();

    // reduce rows [16ks..+16) over 8 slices + vin + tanh -> Gsw[t] A-image.
    // Part addresses are REUSED every step -> must bypass (possibly stale)
    // L1/L2: sc0 sc1 loads read the LLC directly.
    {
      const float* pb = Part + (((size_t)(gt * 8)) << 14) + (rbred << 7) + gl;
      f32x4 pv[8];
#pragma unroll
      for (int j = 0; j < 8; j++) {
        asm volatile("global_load_dwordx4 %0, %1, off sc0 sc1"
                     : "=v"(pv[j])
                     : "v"(pb + ((size_t)j << 14))
                     : "memory");
      }
      asm volatile("s_waitcnt vmcnt(0)" ::: "memory");
      __builtin_amdgcn_sched_barrier(0);  // rule #18: keep VALU below the waitcnt
      float s0 = 0.f, s1 = 0.f, s2 = 0.f, s3 = 0.f;
#pragma unroll
      for (int j = 0; j < 8; j++) {
        s0 += pv[j][0]; s1 += pv[j][1]; s2 += pv[j][2]; s3 += pv[j][3];
      }
      const float v0 = v[(rbred * kT + t) * 2 + 0];
      const float v1 = v[(rbred * kT + t) * 2 + 1];
      const float4 w0 = *(const float4*)(Wih + gg * 2);
      const float4 w1 = *(const float4*)(Wih + gg * 2 + 4);
      const uint16_t h0 = f2bf(fast_tanh(s0 + v0 * w0.x + v1 * w0.y));
      const uint16_t h1 = f2bf(fast_tanh(s1 + v0 * w0.z + v1 * w0.w));
      const uint16_t h2 = f2bf(fast_tanh(s2 + v0 * w1.x + v1 * w1.y));
      const uint16_t h3 = f2bf(fast_tanh(s3 + v0 * w1.z + v1 * w1.w));
      uint2 u;
      u.x = (uint32_t)h0 | ((uint32_t)h1 << 16);
      u.y = (uint32_t)h2 | ((uint32_t)h3 << 16);
      uint16_t* Gt = Gsw + (((size_t)t) << 19);
      *(uint2*)(Gt + a_img_off(rbred, gg)) = u;
    }
    __syncthreads();  // h stores + Part reads complete
    if (tid == 0)
      __hip_atomic_fetch_add(hcnt + (gt << 5), 1, __ATOMIC_RELEASE, __HIP_MEMORY_SCOPE_AGENT);
  }
}

// ---- fallback step kernels (used only if cooperative launch is refused) ----
__global__ __launch_bounds__(512, 4) void stepmm_kernel(const uint16_t* __restrict__ Asrc,
                                                        const uint16_t* __restrict__ WhS,
                                                        float* __restrict__ Part) {
  __shared__ alignas(16) uint16_t lds[32768];
  const int tid = threadIdx.x;
  const int wave = tid >> 6, lane = tid & 63;
  const int gt = blockIdx.x >> 3, ks = blockIdx.x & 7;
  const int mg = wave >> 1, ng = wave & 1;
  const uint16_t* Wbase = WhS + ((size_t)gt << 19);
  f32x4 acc[2][4];
#pragma unroll
  for (int i = 0; i < 2; i++)
#pragma unroll
    for (int j = 0; j < 4; j++) acc[i][j] = (f32x4){0.f, 0.f, 0.f, 0.f};

  for (int kc = 0; kc < 4; kc++) {
    const int chunk = ks * 4 + kc;
    const uint16_t* Ac = Asrc + ((size_t)chunk << 14);
    const uint16_t* Bc = Wbase + ((size_t)chunk << 14);
#pragma unroll
    for (int i = 0; i < 8; i++) {
      const int j = wave * 8 + i;
      const uint16_t* s = (j < 32) ? (Ac + (j << 9)) : (Bc + ((j - 32) << 9));
      gl2lds16(s + (lane << 3), (void*)(lds + (j << 9)));
    }
    __syncthreads();
    const uint16_t* lA = lds;
    const uint16_t* lB = lds + 16384;
#pragma unroll
    for (int ktl = 0; ktl < 4; ktl++) {
      bf16x8 a0 = *(const bf16x8*)(lA + ((((mg * 2 + 0) * 4 + ktl) * 64 + lane) << 3));
      bf16x8 a1 = *(const bf16x8*)(lA + ((((mg * 2 + 1) * 4 + ktl) * 64 + lane) << 3));
#pragma unroll
      for (int nt = 0; nt < 4; nt++) {
        bf16x8 b = *(const bf16x8*)(lB + ((((ng * 4 + nt) * 4 + ktl) * 64 + lane) << 3));
        acc[0][nt] = __builtin_amdgcn_mfma_f32_16x16x32_bf16(a0, b, acc[0][nt], 0, 0, 0);
        acc[1][nt] = __builtin_amdgcn_mfma_f32_16x16x32_bf16(a1, b, acc[1][nt], 0, 0, 0);
      }
    }
    __syncthreads();
  }
  const int g0 = (gt << 7) + (ng << 6);
  const int rb = (mg << 5) + ((lane >> 4) << 2);
#pragma unroll
  for (int mi = 0; mi < 2; mi++)
#pragma unroll
    for (int nt = 0; nt < 4; nt++)
#pragma unroll
      for (int r = 0; r < 4; r++) {
        const int b = rb + (mi << 4) + r;
        const int g = g0 + (nt << 4) + (lane & 15);
        Part[(((size_t)(ks * 128 + b)) << 12) + g] = acc[mi][nt][r];
      }
}

__global__ __launch_bounds__(256) void steptanh_kernel(const float* __restrict__ Part,
                                                       const float* __restrict__ v,
                                                       const float* __restrict__ Wih,
                                                       uint16_t* __restrict__ Gt, int t) {
  const int tg = blockIdx.x * 256 + threadIdx.x;
  const int b = tg >> 9;
  const int g0 = (tg & 511) << 3;
  float s[8];
#pragma unroll
  for (int j = 0; j < 8; j++) s[j] = 0.f;
#pragma unroll
  for (int ks = 0; ks < 8; ks++) {
    const float4* p = (const float4*)(Part + (((size_t)(ks * 128 + b)) << 12) + g0);
    const float4 x = p[0], y = p[1];
    s[0] += x.x; s[1] += x.y; s[2] += x.z; s[3] += x.w;
    s[4] += y.x; s[5] += y.y; s[6] += y.z; s[7] += y.w;
  }
  const float v0 = v[(b * kT + t) * 2 + 0];
  const float v1 = v[(b * kT + t) * 2 + 1];
  uint16_t h[8];
#pragma unroll
  for (int j = 0; j < 8; j++) {
    const int g = g0 + j;
    const float pre = s[j] + v0 * Wih[g * 2 + 0] + v1 * Wih[g * 2 + 1];
    h[j] = f2bf(fast_tanh(pre));
  }
  uint4 u;
  u.x = (uint32_t)h[0] | ((uint32_t)h[1] << 16);
  u.y = (uint32_t)h[2] | ((uint32_t)h[3] << 16);
  u.z = (uint32_t)h[4] | ((uint32_t)h[5] << 16);
  u.w = (uint32_t)h[6] | ((uint32_t)h[7] << 16);
  const size_t off = ((size_t)(((g0 >> 7) * 8 + (b >> 4)) * 4 + ((g0 >> 5) & 3)) * 64 +
                      ((g0 >> 3) & 3) * 16 + (b & 15)) * 8;
  *(uint4*)(Gt + off) = u;
}

// ---- decoder: out[b,t,p] = Gsw[t] @ WdS[pt] + bias. block=(t, pt), 32 k-chunks ----
__global__ __launch_bounds__(512, 4) void dec_kernel(const uint16_t* __restrict__ Gsw,
                                                     const uint16_t* __restrict__ WdS,
                                                     const float* __restrict__ bd,
                                                     float* __restrict__ out) {
  __shared__ alignas(16) uint16_t lds[32768];
  const int tid = threadIdx.x;
  const int wave = tid >> 6, lane = tid & 63;
  const int t = blockIdx.x >> 2, pt = blockIdx.x & 3;
  const int mg = wave >> 1, ng = wave & 1;
  const uint16_t* Abase = Gsw + (size_t)t * 524288;
  const uint16_t* Bbase = WdS + (size_t)pt * 524288;
  f32x4 acc[2][4];
#pragma unroll
  for (int i = 0; i < 2; i++)
#pragma unroll
    for (int j = 0; j < 4; j++) acc[i][j] = (f32x4){0.f, 0.f, 0.f, 0.f};

  for (int chunk = 0; chunk < 32; chunk++) {
    const uint16_t* Ac = Abase + ((size_t)chunk << 14);
    const uint16_t* Bc = Bbase + ((size_t)chunk << 14);
#pragma unroll
    for (int i = 0; i < 8; i++) {
      const int j = wave * 8 + i;
      const uint16_t* s = (j < 32) ? (Ac + (j << 9)) : (Bc + ((j - 32) << 9));
      gl2lds16(s + (lane << 3), (void*)(lds + (j << 9)));
    }
    __syncthreads();
    const uint16_t* lA = lds;
    const uint16_t* lB = lds + 16384;
#pragma unroll
    for (int ktl = 0; ktl < 4; ktl++) {
      bf16x8 a0 = *(const bf16x8*)(lA + ((((mg * 2 + 0) * 4 + ktl) * 64 + lane) << 3));
      bf16x8 a1 = *(const bf16x8*)(lA + ((((mg * 2 + 1) * 4 + ktl) * 64 + lane) << 3));
#pragma unroll
      for (int nt = 0; nt < 4; nt++) {
        bf16x8 b = *(const bf16x8*)(lB + ((((ng * 4 + nt) * 4 + ktl) * 64 + lane) << 3));
        acc[0][nt] = __builtin_amdgcn_mfma_f32_16x16x32_bf16(a0, b, acc[0][nt], 0, 0, 0);
        acc[1][nt] = __builtin_amdgcn_mfma_f32_16x16x32_bf16(a1, b, acc[1][nt], 0, 0, 0);
      }
    }
    __syncthreads();
  }
  const int p0c = (pt << 7) + (ng << 6);
  const int rb = (mg << 5) + ((lane >> 4) << 2);
#pragma unroll
  for (int mi = 0; mi < 2; mi++)
#pragma unroll
    for (int nt = 0; nt < 4; nt++) {
      const int p = p0c + (nt << 4) + (lane & 15);
      const float bias = bd[p];
#pragma unroll
      for (int r = 0; r < 4; r++) {
        const int b = rb + (mi << 4) + r;
        out[((size_t)b * kT + t) * kNP + p] = acc[mi][nt][r] + bias;
      }
    }
}

extern "C" void kernel_launch(void* const* d_in, const int* in_sizes, int n_in,
                              void* d_out, int out_size, void* d_ws, size_t ws_size,
                              hipStream_t stream) {
  const float* v    = (const float*)d_in[0];
  const float* p0   = (const float*)d_in[1];
  const float* Wenc = (const float*)d_in[2];
  const float* Wih  = (const float*)d_in[3];
  const float* Whh  = (const float*)d_in[4];
  const float* Wdec = (const float*)d_in[5];
  const float* bdec = (const float*)d_in[6];
  float* out = (float*)d_out;

  uint8_t* ws = (uint8_t*)d_ws;
  uint16_t* WhS = (uint16_t*)(ws);
  uint16_t* WdS = (uint16_t*)(ws + 33554432);
  uint16_t* H0S = (uint16_t*)(ws + 37748736);
  uint16_t* Gsw = (uint16_t*)(ws + 38797312);
  float*    Part = (float*)(ws + 143654912);
  int*      flags = (int*)(ws + 160432128);

  cvt_whh_kernel<<<4096, 512, 0, stream>>>(Whh, WhS, flags);
  cvt_wdec_kernel<<<512, 512, 0, stream>>>(Wdec, WdS);
  enc_kernel<<<256, 512, 0, stream>>>(p0, Wenc, H0S);

  // persistent flag-synced RNN loop (cooperative launch for residency guarantee)
  const uint16_t* WhS_c = WhS;
  const uint16_t* H0S_c = H0S;
  void* args[7] = {(void*)&WhS_c, (void*)&H0S_c, (void*)&Gsw, (void*)&Part,
                   (void*)&v, (void*)&Wih, (void*)&flags};
  hipError_t e = hipLaunchCooperativeKernel(rnn_loop_kernel, dim3(256), dim3(512), args,
                                            (unsigned int)131072, stream);
  if (e != hipSuccess) {
    // fallback: per-step launches (round-1 path, ~1.96 ms class)
    (void)hipGetLastError();
    for (int t = 0; t < kT; t++) {
      const uint16_t* Asrc = (t == 0) ? H0S : (Gsw + (size_t)(t - 1) * 524288);
      stepmm_kernel<<<256, 512, 0, stream>>>(Asrc, WhS, Part);
      steptanh_kernel<<<256, 256, 0, stream>>>(Part, v, Wih, Gsw + (size_t)t * 524288, t);
    }
  }

  dec_kernel<<<400, 512, 0, stream>>>(Gsw, WdS, bdec, out);
}

// Round 5
// 1150.589 us; speedup vs baseline: 6.8105x; 2.1467x over previous
//
// RNN_79577154060490 — round 6: topology-aware sync. Part = intra-XCD via shared
// L2 (sc0 reads, relaxed flags); h = cross-XCD via LLC-point atomic swaps.
// h0 = p0@W_enc^T; 100x h=tanh(v@W_ih^T + h@W_hh^T); out = g@W_dec^T + b
//
// Round-5 post-mortem: sc0sc1 stores do NOT write through L2 on gfx950 (absmax
// 2.95): data stayed dirty in producer L2, LLC had stale lines. But flags
// (agent-scope atomics) always propagated -> atomics execute at the LLC.
// Round-6 protocol (zero cache-maintenance ops, correct by construction):
//  * Part[gt]: producers==consumers==same XCD (block remap). L1 is write-through
//    so store->vmcnt(0) puts data in the SHARED L2; consumers read with `sc0`
//    (bypass own stale L1, hit L2). pcnt adds RELAXED.
//  * h: per-thread 8B fragment published via __hip_atomic_exchange (AGENT,
//    RELAXED) -> executes at LLC (same proven mechanism as the flags). vmcnt(0)
//    then RELAXED hcnt add. Consumers plain-load (fresh addresses each t;
//    dispatch-start invalidate covers graph replays — validated rounds 1-4).
//  * W_hh stays LDS-resident (128 KB/block, loaded once).
//
// ws layout (bytes):
//   [0,         33554432)   WhS  bf16 [gt32][chunk32][nt8][ktl4][64][8]
//   [33554432,  37748736)   WdS  bf16 [pt4][chunk32][nt8][ktl4][64][8]
//   [37748736,  38797312)   H0S  bf16 A-image (1MB)
//   [38797312, 143654912)   Gsw  bf16 [t100] A-images (100MB)
//   [143654912,160432128)   Part fp32 [gt32][ks8][128][128] (16MB)
//   [160432128,160440320)   flags int[2048] (pcnt[32], hcnt[32]; stride 32)

#include <hip/hip_runtime.h>
#include <stdint.h>

namespace {
constexpr int kT = 100;
constexpr int kNG = 4096;
constexpr int kNP = 512;

__device__ __forceinline__ uint16_t f2bf(float f) {
  uint32_t u = __float_as_uint(f);
  u += 0x7FFFu + ((u >> 16) & 1u);
  return (uint16_t)(u >> 16);
}

__device__ __forceinline__ float fast_tanh(float x) {
  float xc = fminf(fmaxf(x, -15.f), 15.f);
  float e = __expf(2.f * xc);
  return (e - 1.f) / (e + 1.f);
}

__device__ __forceinline__ void gl2lds16(const void* g, void* l) {
  __builtin_amdgcn_global_load_lds((const __attribute__((address_space(1))) unsigned int*)g,
                                   (__attribute__((address_space(3))) unsigned int*)l, 16, 0, 0);
}

// fragment-image element offsets (within one tensor)
__device__ __forceinline__ size_t a_img_off(int b, int g) {  // g = k index
  return ((size_t)(((g >> 7) * 8 + (b >> 4)) * 4 + ((g >> 5) & 3)) * 64 +
          ((g >> 3) & 3) * 16 + (b & 15)) * 8 + (g & 7);
}
}  // namespace

typedef short bf16x8 __attribute__((ext_vector_type(8)));
typedef float f32x4 __attribute__((ext_vector_type(4)));

// ---- swizzle-convert W_hh fp32 [4096][4096] -> WhS B-image bf16 (+flag zero) ----
__global__ __launch_bounds__(512) void cvt_whh_kernel(const float* __restrict__ W,
                                                      uint16_t* __restrict__ WhS,
                                                      int* __restrict__ flags) {
  if (blockIdx.x == 4095) {
    for (int i = threadIdx.x; i < 2048; i += 512) flags[i] = 0;
  }
  const int idx = blockIdx.x * 512 + threadIdx.x;  // 2M threads
  const int g = idx >> 9;
  const int k0 = (idx & 511) << 3;
  const float4 x = *(const float4*)(W + (size_t)g * kNG + k0);
  const float4 y = *(const float4*)(W + (size_t)g * kNG + k0 + 4);
  uint4 u;
  u.x = (uint32_t)f2bf(x.x) | ((uint32_t)f2bf(x.y) << 16);
  u.y = (uint32_t)f2bf(x.z) | ((uint32_t)f2bf(x.w) << 16);
  u.z = (uint32_t)f2bf(y.x) | ((uint32_t)f2bf(y.y) << 16);
  u.w = (uint32_t)f2bf(y.z) | ((uint32_t)f2bf(y.w) << 16);
  const int gt = g >> 7, c = g & 127;
  const int nt = c >> 4, col = c & 15;
  const int chunk = k0 >> 7, ktl = (k0 >> 5) & 3, half = (k0 >> 3) & 3;
  const size_t off = ((size_t)(((gt * 32 + chunk) * 8 + nt) * 4 + ktl) * 64 + half * 16 + col) * 8;
  *(uint4*)(WhS + off) = u;
}

// ---- swizzle-convert W_dec fp32 [512][4096] -> WdS B-image bf16 ----
__global__ __launch_bounds__(512) void cvt_wdec_kernel(const float* __restrict__ W,
                                                       uint16_t* __restrict__ WdS) {
  const int idx = blockIdx.x * 512 + threadIdx.x;  // 256K threads
  const int p = idx >> 9;
  const int k0 = (idx & 511) << 3;
  const float4 x = *(const float4*)(W + (size_t)p * kNG + k0);
  const float4 y = *(const float4*)(W + (size_t)p * kNG + k0 + 4);
  uint4 u;
  u.x = (uint32_t)f2bf(x.x) | ((uint32_t)f2bf(x.y) << 16);
  u.y = (uint32_t)f2bf(x.z) | ((uint32_t)f2bf(x.w) << 16);
  u.z = (uint32_t)f2bf(y.x) | ((uint32_t)f2bf(y.y) << 16);
  u.w = (uint32_t)f2bf(y.z) | ((uint32_t)f2bf(y.w) << 16);
  const int pt = p >> 7, c = p & 127;
  const int nt = c >> 4, col = c & 15;
  const int chunk = k0 >> 7, ktl = (k0 >> 5) & 3, half = (k0 >> 3) & 3;
  const size_t off = ((size_t)(((pt * 32 + chunk) * 8 + nt) * 4 + ktl) * 64 + half * 16 + col) * 8;
  *(uint4*)(WdS + off) = u;
}

// ---- encoder: H0S = A-image of p0 @ Wenc^T (bf16) ----
__global__ __launch_bounds__(512, 2) void enc_kernel(const float* __restrict__ p0,
                                                     const float* __restrict__ Wenc,
                                                     uint16_t* __restrict__ H0S) {
  __shared__ alignas(16) uint16_t Wlds[16 * 64 * 8];
  const int tid = threadIdx.x;
  const int g0 = blockIdx.x * 16;
  for (int f = tid; f < 16 * 64; f += 512) {
    const int kt = f >> 6, fl = f & 63;
    const int g = g0 + (fl & 15);
    const int k = kt * 32 + ((fl >> 4) << 3);
    const float* s = Wenc + (size_t)g * kNP + k;
    uint16_t* d = Wlds + f * 8;
#pragma unroll
    for (int j = 0; j < 8; j++) d[j] = f2bf(s[j]);
  }
  __syncthreads();
  const int wave = tid >> 6;
  const int lane = tid & 63;
  const int mrow = wave * 16 + (lane & 15);
  const float* arow = p0 + (size_t)mrow * kNP + ((lane >> 4) << 3);
  f32x4 acc = {0.f, 0.f, 0.f, 0.f};
#pragma unroll
  for (int kt = 0; kt < 16; kt++) {
    const float* ap = arow + kt * 32;
    bf16x8 a;
#pragma unroll
    for (int j = 0; j < 8; j++) a[j] = (short)f2bf(ap[j]);
    bf16x8 b = *(const bf16x8*)(Wlds + (kt * 64 + lane) * 8);
    acc = __builtin_amdgcn_mfma_f32_16x16x32_bf16(a, b, acc, 0, 0, 0);
  }
  const int gcol = g0 + (lane & 15);
  const int rbase = wave * 16 + ((lane >> 4) << 2);
#pragma unroll
  for (int r = 0; r < 4; r++) {
    H0S[a_img_off(rbase + r, gcol)] = f2bf(acc[r]);
  }
}

// ---- persistent RNN loop, flag-synced; topology-aware data movement ----
__global__ __launch_bounds__(512, 2) void rnn_loop_kernel(const uint16_t* __restrict__ WhS,
                                                          const uint16_t* __restrict__ H0S,
                                                          uint16_t* __restrict__ Gsw,
                                                          float* __restrict__ Part,
                                                          const float* __restrict__ v,
                                                          const float* __restrict__ Wih,
                                                          int* __restrict__ flags) {
  extern __shared__ uint16_t wlds[];  // 131072 B
  const int tid = threadIdx.x;
  const int wave = tid >> 6, lane = tid & 63;
  const int bid = blockIdx.x;
  const int xcd = bid & 7;                 // dispatch round-robin heuristic (perf-only)
  const int gt = xcd * 4 + (bid >> 6);     // all 8 ks-blocks of gt on one XCD
  const int ks = (bid >> 3) & 7;
  const int mg = wave >> 1, ng = wave & 1;

  int* pcnt = flags;            // [gt] stride 32
  int* hcnt = flags + 32 * 32;  // [gt] stride 32

  // one-time: W tile (row gt, chunks ks*4..+3) -> LDS, linear copy
  {
    const uint16_t* src = WhS + ((size_t)gt << 19) + ((size_t)(ks * 4) << 14);
#pragma unroll
    for (int i = 0; i < 16; i++) {
      const int j = wave * 16 + i;
      gl2lds16(src + (j << 9) + (lane << 3), (void*)(wlds + (j << 9)));
    }
  }
  __syncthreads();

  // reduce-phase coords: 16 rows x 128 g per block, 4 g per thread
  const int rbred = ks * 16 + (tid >> 5);  // batch row
  const int gl = (tid & 31) << 2;          // local g 0..124
  const int gg = gt * 128 + gl;            // global g
  float* myPart = Part + (((size_t)(gt * 8 + ks)) << 14);

  for (int t = 0; t < kT; t++) {
    // wait: h(t-1) chunks 4ks..4ks+3 ready; hcnt[gt] doubles as Part WAR gate
    if (t > 0) {
      const int target = 8 * t;
      if (tid < 5) {
        int* f = (tid < 4) ? (hcnt + ((ks * 4 + tid) << 5)) : (hcnt + (gt << 5));
        while (__hip_atomic_load(f, __ATOMIC_RELAXED, __HIP_MEMORY_SCOPE_AGENT) < target)
          __builtin_amdgcn_s_sleep(1);
      }
      __builtin_amdgcn_fence(__ATOMIC_ACQUIRE, "workgroup");  // compiler order; no cache op
      __syncthreads();
    }

    const uint16_t* Aimg = (t == 0) ? H0S : (Gsw + (((size_t)(t - 1)) << 19));
    f32x4 acc[2][4];
#pragma unroll
    for (int i = 0; i < 2; i++)
#pragma unroll
      for (int j = 0; j < 4; j++) acc[i][j] = (f32x4){0.f, 0.f, 0.f, 0.f};

#pragma unroll
    for (int kc = 0; kc < 4; kc++) {
      const uint16_t* Ac = Aimg + ((size_t)(ks * 4 + kc) << 14);
      bf16x8 a[2][4];
#pragma unroll
      for (int mi = 0; mi < 2; mi++)
#pragma unroll
        for (int ktl = 0; ktl < 4; ktl++)
          a[mi][ktl] = *(const bf16x8*)(Ac + ((((mg * 2 + mi) * 4 + ktl) * 64 + lane) << 3));
#pragma unroll
      for (int ktl = 0; ktl < 4; ktl++) {
#pragma unroll
        for (int nt = 0; nt < 4; nt++) {
          bf16x8 b = *(const bf16x8*)(wlds + (kc << 14) +
                                      ((((ng * 4 + nt) * 4 + ktl) * 64 + lane) << 3));
          acc[0][nt] = __builtin_amdgcn_mfma_f32_16x16x32_bf16(a[0][ktl], b, acc[0][nt], 0, 0, 0);
          acc[1][nt] = __builtin_amdgcn_mfma_f32_16x16x32_bf16(a[1][ktl], b, acc[1][nt], 0, 0, 0);
        }
      }
    }
    // Part write: NORMAL stores. L1 is write-through, so after vmcnt(0) the data
    // is in the XCD-shared L2 — exactly where the (same-XCD) consumers read it.
    {
      const int gcol0 = (ng << 6);
      const int rbase = (mg << 5) + ((lane >> 4) << 2);
#pragma unroll
      for (int mi = 0; mi < 2; mi++)
#pragma unroll
        for (int nt = 0; nt < 4; nt++)
#pragma unroll
          for (int r = 0; r < 4; r++) {
            const int b = rbase + (mi << 4) + r;
            const int g = gcol0 + (nt << 4) + (lane & 15);
            myPart[(b << 7) + g] = acc[mi][nt][r];
          }
    }
    asm volatile("s_waitcnt vmcnt(0)" ::: "memory");  // Part committed to shared L2
    __syncthreads();
    if (tid == 0) {
      // publish Part to same-XCD peers: RELAXED add (no wbl2 — data is in L2)
      __hip_atomic_fetch_add(pcnt + (gt << 5), 1, __ATOMIC_RELAXED, __HIP_MEMORY_SCOPE_AGENT);
      const int tgt = 8 * (t + 1);
      while (__hip_atomic_load(pcnt + (gt << 5), __ATOMIC_RELAXED, __HIP_MEMORY_SCOPE_AGENT) < tgt)
        __builtin_amdgcn_s_sleep(1);
      __builtin_amdgcn_fence(__ATOMIC_ACQUIRE, "workgroup");  // compiler order only
    }
    __syncthreads();

    // reduce rows [16ks..+16) over 8 slices + vin + tanh -> Gsw[t] A-image.
    // Part reads: `sc0` = bypass own (stale) L1, hit the shared L2.
    {
      const float* pb = Part + (((size_t)(gt * 8)) << 14) + (rbred << 7) + gl;
      f32x4 pv[8];
#pragma unroll
      for (int j = 0; j < 8; j++) {
        asm volatile("global_load_dwordx4 %0, %1, off sc0"
                     : "=v"(pv[j])
                     : "v"(pb + ((size_t)j << 14))
                     : "memory");
      }
      asm volatile("s_waitcnt vmcnt(0)" ::: "memory");
      __builtin_amdgcn_sched_barrier(0);  // rule #18: keep VALU below the waitcnt
      float s0 = 0.f, s1 = 0.f, s2 = 0.f, s3 = 0.f;
#pragma unroll
      for (int j = 0; j < 8; j++) {
        s0 += pv[j][0]; s1 += pv[j][1]; s2 += pv[j][2]; s3 += pv[j][3];
      }
      const float v0 = v[(rbred * kT + t) * 2 + 0];
      const float v1 = v[(rbred * kT + t) * 2 + 1];
      const float4 w0 = *(const float4*)(Wih + gg * 2);
      const float4 w1 = *(const float4*)(Wih + gg * 2 + 4);
      const uint16_t h0 = f2bf(fast_tanh(s0 + v0 * w0.x + v1 * w0.y));
      const uint16_t h1 = f2bf(fast_tanh(s1 + v0 * w0.z + v1 * w0.w));
      const uint16_t h2 = f2bf(fast_tanh(s2 + v0 * w1.x + v1 * w1.y));
      const uint16_t h3 = f2bf(fast_tanh(s3 + v0 * w1.z + v1 * w1.w));
      const uint32_t lo = (uint32_t)h0 | ((uint32_t)h1 << 16);
      const uint32_t hi = (uint32_t)h2 | ((uint32_t)h3 << 16);
      const unsigned long long uval = ((unsigned long long)hi << 32) | lo;
      uint16_t* Gt = Gsw + (((size_t)t) << 19);
      // h store: atomic swap executes at the LLC (agent coherence point) ->
      // cross-XCD readers' L2 misses fetch the fresh value. No wbl2 needed.
      __hip_atomic_exchange((unsigned long long*)(Gt + a_img_off(rbred, gg)), uval,
                            __ATOMIC_RELAXED, __HIP_MEMORY_SCOPE_AGENT);
    }
    asm volatile("s_waitcnt vmcnt(0)" ::: "memory");  // h swap done; Part reads consumed
    __syncthreads();
    if (tid == 0)
      __hip_atomic_fetch_add(hcnt + (gt << 5), 1, __ATOMIC_RELAXED, __HIP_MEMORY_SCOPE_AGENT);
  }
}

// ---- fallback step kernels (used only if cooperative launch is refused) ----
__global__ __launch_bounds__(512, 4) void stepmm_kernel(const uint16_t* __restrict__ Asrc,
                                                        const uint16_t* __restrict__ WhS,
                                                        float* __restrict__ Part) {
  __shared__ alignas(16) uint16_t lds[32768];
  const int tid = threadIdx.x;
  const int wave = tid >> 6, lane = tid & 63;
  const int gt = blockIdx.x >> 3, ks = blockIdx.x & 7;
  const int mg = wave >> 1, ng = wave & 1;
  const uint16_t* Wbase = WhS + ((size_t)gt << 19);
  f32x4 acc[2][4];
#pragma unroll
  for (int i = 0; i < 2; i++)
#pragma unroll
    for (int j = 0; j < 4; j++) acc[i][j] = (f32x4){0.f, 0.f, 0.f, 0.f};

  for (int kc = 0; kc < 4; kc++) {
    const int chunk = ks * 4 + kc;
    const uint16_t* Ac = Asrc + ((size_t)chunk << 14);
    const uint16_t* Bc = Wbase + ((size_t)chunk << 14);
#pragma unroll
    for (int i = 0; i < 8; i++) {
      const int j = wave * 8 + i;
      const uint16_t* s = (j < 32) ? (Ac + (j << 9)) : (Bc + ((j - 32) << 9));
      gl2lds16(s + (lane << 3), (void*)(lds + (j << 9)));
    }
    __syncthreads();
    const uint16_t* lA = lds;
    const uint16_t* lB = lds + 16384;
#pragma unroll
    for (int ktl = 0; ktl < 4; ktl++) {
      bf16x8 a0 = *(const bf16x8*)(lA + ((((mg * 2 + 0) * 4 + ktl) * 64 + lane) << 3));
      bf16x8 a1 = *(const bf16x8*)(lA + ((((mg * 2 + 1) * 4 + ktl) * 64 + lane) << 3));
#pragma unroll
      for (int nt = 0; nt < 4; nt++) {
        bf16x8 b = *(const bf16x8*)(lB + ((((ng * 4 + nt) * 4 + ktl) * 64 + lane) << 3));
        acc[0][nt] = __builtin_amdgcn_mfma_f32_16x16x32_bf16(a0, b, acc[0][nt], 0, 0, 0);
        acc[1][nt] = __builtin_amdgcn_mfma_f32_16x16x32_bf16(a1, b, acc[1][nt], 0, 0, 0);
      }
    }
    __syncthreads();
  }
  const int g0 = (gt << 7) + (ng << 6);
  const int rb = (mg << 5) + ((lane >> 4) << 2);
#pragma unroll
  for (int mi = 0; mi < 2; mi++)
#pragma unroll
    for (int nt = 0; nt < 4; nt++)
#pragma unroll
      for (int r = 0; r < 4; r++) {
        const int b = rb + (mi << 4) + r;
        const int g = g0 + (nt << 4) + (lane & 15);
        Part[(((size_t)(ks * 128 + b)) << 12) + g] = acc[mi][nt][r];
      }
}

__global__ __launch_bounds__(256) void steptanh_kernel(const float* __restrict__ Part,
                                                       const float* __restrict__ v,
                                                       const float* __restrict__ Wih,
                                                       uint16_t* __restrict__ Gt, int t) {
  const int tg = blockIdx.x * 256 + threadIdx.x;
  const int b = tg >> 9;
  const int g0 = (tg & 511) << 3;
  float s[8];
#pragma unroll
  for (int j = 0; j < 8; j++) s[j] = 0.f;
#pragma unroll
  for (int ks = 0; ks < 8; ks++) {
    const float4* p = (const float4*)(Part + (((size_t)(ks * 128 + b)) << 12) + g0);
    const float4 x = p[0], y = p[1];
    s[0] += x.x; s[1] += x.y; s[2] += x.z; s[3] += x.w;
    s[4] += y.x; s[5] += y.y; s[6] += y.z; s[7] += y.w;
  }
  const float v0 = v[(b * kT + t) * 2 + 0];
  const float v1 = v[(b * kT + t) * 2 + 1];
  uint16_t h[8];
#pragma unroll
  for (int j = 0; j < 8; j++) {
    const int g = g0 + j;
    const float pre = s[j] + v0 * Wih[g * 2 + 0] + v1 * Wih[g * 2 + 1];
    h[j] = f2bf(fast_tanh(pre));
  }
  uint4 u;
  u.x = (uint32_t)h[0] | ((uint32_t)h[1] << 16);
  u.y = (uint32_t)h[2] | ((uint32_t)h[3] << 16);
  u.z = (uint32_t)h[4] | ((uint32_t)h[5] << 16);
  u.w = (uint32_t)h[6] | ((uint32_t)h[7] << 16);
  const size_t off = ((size_t)(((g0 >> 7) * 8 + (b >> 4)) * 4 + ((g0 >> 5) & 3)) * 64 +
                      ((g0 >> 3) & 3) * 16 + (b & 15)) * 8;
  *(uint4*)(Gt + off) = u;
}

// ---- decoder: out[b,t,p] = Gsw[t] @ WdS[pt] + bias. block=(t, pt), 32 k-chunks ----
__global__ __launch_bounds__(512, 4) void dec_kernel(const uint16_t* __restrict__ Gsw,
                                                     const uint16_t* __restrict__ WdS,
                                                     const float* __restrict__ bd,
                                                     float* __restrict__ out) {
  __shared__ alignas(16) uint16_t lds[32768];
  const int tid = threadIdx.x;
  const int wave = tid >> 6, lane = tid & 63;
  const int t = blockIdx.x >> 2, pt = blockIdx.x & 3;
  const int mg = wave >> 1, ng = wave & 1;
  const uint16_t* Abase = Gsw + (size_t)t * 524288;
  const uint16_t* Bbase = WdS + (size_t)pt * 524288;
  f32x4 acc[2][4];
#pragma unroll
  for (int i = 0; i < 2; i++)
#pragma unroll
    for (int j = 0; j < 4; j++) acc[i][j] = (f32x4){0.f, 0.f, 0.f, 0.f};

  for (int chunk = 0; chunk < 32; chunk++) {
    const uint16_t* Ac = Abase + ((size_t)chunk << 14);
    const uint16_t* Bc = Bbase + ((size_t)chunk << 14);
#pragma unroll
    for (int i = 0; i < 8; i++) {
      const int j = wave * 8 + i;
      const uint16_t* s = (j < 32) ? (Ac + (j << 9)) : (Bc + ((j - 32) << 9));
      gl2lds16(s + (lane << 3), (void*)(lds + (j << 9)));
    }
    __syncthreads();
    const uint16_t* lA = lds;
    const uint16_t* lB = lds + 16384;
#pragma unroll
    for (int ktl = 0; ktl < 4; ktl++) {
      bf16x8 a0 = *(const bf16x8*)(lA + ((((mg * 2 + 0) * 4 + ktl) * 64 + lane) << 3));
      bf16x8 a1 = *(const bf16x8*)(lA + ((((mg * 2 + 1) * 4 + ktl) * 64 + lane) << 3));
#pragma unroll
      for (int nt = 0; nt < 4; nt++) {
        bf16x8 b = *(const bf16x8*)(lB + ((((ng * 4 + nt) * 4 + ktl) * 64 + lane) << 3));
        acc[0][nt] = __builtin_amdgcn_mfma_f32_16x16x32_bf16(a0, b, acc[0][nt], 0, 0, 0);
        acc[1][nt] = __builtin_amdgcn_mfma_f32_16x16x32_bf16(a1, b, acc[1][nt], 0, 0, 0);
      }
    }
    __syncthreads();
  }
  const int p0c = (pt << 7) + (ng << 6);
  const int rb = (mg << 5) + ((lane >> 4) << 2);
#pragma unroll
  for (int mi = 0; mi < 2; mi++)
#pragma unroll
    for (int nt = 0; nt < 4; nt++) {
      const int p = p0c + (nt << 4) + (lane & 15);
      const float bias = bd[p];
#pragma unroll
      for (int r = 0; r < 4; r++) {
        const int b = rb + (mi << 4) + r;
        out[((size_t)b * kT + t) * kNP + p] = acc[mi][nt][r] + bias;
      }
    }
}

extern "C" void kernel_launch(void* const* d_in, const int* in_sizes, int n_in,
                              void* d_out, int out_size, void* d_ws, size_t ws_size,
                              hipStream_t stream) {
  const float* v    = (const float*)d_in[0];
  const float* p0   = (const float*)d_in[1];
  const float* Wenc = (const float*)d_in[2];
  const float* Wih  = (const float*)d_in[3];
  const float* Whh  = (const float*)d_in[4];
  const float* Wdec = (const float*)d_in[5];
  const float* bdec = (const float*)d_in[6];
  float* out = (float*)d_out;

  uint8_t* ws = (uint8_t*)d_ws;
  uint16_t* WhS = (uint16_t*)(ws);
  uint16_t* WdS = (uint16_t*)(ws + 33554432);
  uint16_t* H0S = (uint16_t*)(ws + 37748736);
  uint16_t* Gsw = (uint16_t*)(ws + 38797312);
  float*    Part = (float*)(ws + 143654912);
  int*      flags = (int*)(ws + 160432128);

  cvt_whh_kernel<<<4096, 512, 0, stream>>>(Whh, WhS, flags);
  cvt_wdec_kernel<<<512, 512, 0, stream>>>(Wdec, WdS);
  enc_kernel<<<256, 512, 0, stream>>>(p0, Wenc, H0S);

  // persistent flag-synced RNN loop (cooperative launch for residency guarantee)
  const uint16_t* WhS_c = WhS;
  const uint16_t* H0S_c = H0S;
  void* args[7] = {(void*)&WhS_c, (void*)&H0S_c, (void*)&Gsw, (void*)&Part,
                   (void*)&v, (void*)&Wih, (void*)&flags};
  hipError_t e = hipLaunchCooperativeKernel(rnn_loop_kernel, dim3(256), dim3(512), args,
                                            (unsigned int)131072, stream);
  if (e != hipSuccess) {
    // fallback: per-step launches (round-1 path, ~1.96 ms class)
    (void)hipGetLastError();
    for (int t = 0; t < kT; t++) {
      const uint16_t* Asrc = (t == 0) ? H0S : (Gsw + (size_t)(t - 1) * 524288);
      stepmm_kernel<<<256, 512, 0, stream>>>(Asrc, WhS, Part);
      steptanh_kernel<<<256, 256, 0, stream>>>(Part, v, Wih, Gsw + (size_t)t * 524288, t);
    }
  }

  dec_kernel<<<400, 512, 0, stream>>>(Gsw, WdS, bdec, out);
}